// Round 1
// baseline (15705.511 us; speedup 1.0000x reference)
//
#include <hip/hip_runtime.h>
#include <hip/hip_bf16.h>
#include <math.h>

// ---------------- constants ----------------
static constexpr int E   = 768;
static constexpr int NH  = 12;
static constexpr int HD  = 64;
static constexpr int Bsz = 2;
static constexpr int G   = 32;          // 512/16 patches per side
static constexpr int NTOK = G * G;      // 1024 tokens per image
static constexpr int ROWS = Bsz * NTOK; // 2048 token rows
static constexpr int WS  = 14;          // window size
static constexpr int NWIN_SIDE = 3;     // ceil(32/14)=3 windows per side (padded to 42)
static constexpr int NWIN = NWIN_SIDE * NWIN_SIDE;  // 9 per image
static constexpr int BW  = Bsz * NWIN;  // 18 window-batches
static constexpr int NW  = WS * WS;     // 196 tokens per window
static constexpr int WROWS = BW * NW;   // 3528 windowed rows
static constexpr int WIN_MASK = 0x6DB;  // layers 0,1,3,4,6,7,9,10

// ---------------- LayerNorm ----------------
__global__ __launch_bounds__(256) void ln_kernel(
    const float* __restrict__ in, const float* __restrict__ w,
    const float* __restrict__ b, float* __restrict__ out) {
  __shared__ float2 red[256];
  const int row = blockIdx.x, tid = threadIdx.x;
  const float* r = in + (size_t)row * E;
  float v0 = r[tid], v1 = r[tid + 256], v2 = r[tid + 512];
  float s = v0 + v1 + v2;
  float s2 = v0 * v0 + v1 * v1 + v2 * v2;
  red[tid] = make_float2(s, s2);
  __syncthreads();
  for (int off = 128; off; off >>= 1) {
    if (tid < off) {
      red[tid].x += red[tid + off].x;
      red[tid].y += red[tid + off].y;
    }
    __syncthreads();
  }
  const float mean = red[0].x * (1.f / E);
  const float var  = red[0].y * (1.f / E) - mean * mean;
  const float rs   = rsqrtf(var + 1e-6f);
  float* o = out + (size_t)row * E;
  o[tid]       = (v0 - mean) * rs * w[tid]       + b[tid];
  o[tid + 256] = (v1 - mean) * rs * w[tid + 256] + b[tid + 256];
  o[tid + 512] = (v2 - mean) * rs * w[tid + 512] + b[tid + 512];
}

// ---------------- generic tiled GEMM:  C = A(MxK) * B(KxN) + bias [+res / gelu]
enum { OP_BIAS = 0, OP_GELU = 1, OP_ADD = 2 };

template <int OP>
__global__ __launch_bounds__(256) void gemm_kernel(
    const float* __restrict__ A, const float* __restrict__ Bm,
    const float* __restrict__ bias, const float* __restrict__ res,
    float* __restrict__ C, int M, int N, int K) {
  __shared__ float As[16][68];  // padded: A-store 2-way conflict only (free)
  __shared__ float Bs[16][64];
  const int tid = threadIdx.x;
  const int tx = tid & 15, ty = tid >> 4;
  const int row0 = blockIdx.y * 64, col0 = blockIdx.x * 64;
  float acc[4][4] = {};
  const int la_k = tid & 15, la_r = tid >> 4;   // A tile load mapping
  const int lb_c = tid & 63, lb_k = tid >> 6;   // B tile load mapping

  for (int k0 = 0; k0 < K; k0 += 16) {
#pragma unroll
    for (int i = 0; i < 4; i++) {
      int r = la_r + i * 16;
      int gr = row0 + r;
      As[la_k][r] = (gr < M) ? A[(size_t)gr * K + k0 + la_k] : 0.f;
    }
#pragma unroll
    for (int i = 0; i < 4; i++) {
      int kr = lb_k + i * 4;
      Bs[kr][lb_c] = Bm[(size_t)(k0 + kr) * N + col0 + lb_c];
    }
    __syncthreads();
#pragma unroll
    for (int kk = 0; kk < 16; kk++) {
      const float4 av = *(const float4*)&As[kk][ty * 4];
      const float4 bv = *(const float4*)&Bs[kk][tx * 4];
      const float a[4]  = {av.x, av.y, av.z, av.w};
      const float b4[4] = {bv.x, bv.y, bv.z, bv.w};
#pragma unroll
      for (int i = 0; i < 4; i++)
#pragma unroll
        for (int j = 0; j < 4; j++) acc[i][j] += a[i] * b4[j];
    }
    __syncthreads();
  }

#pragma unroll
  for (int i = 0; i < 4; i++) {
    const int r = row0 + ty * 4 + i;
    if (r >= M) continue;
#pragma unroll
    for (int j = 0; j < 4; j++) {
      const int c = col0 + tx * 4 + j;
      float v = acc[i][j] + bias[c];
      if (OP == OP_GELU) v = 0.5f * v * (1.f + erff(v * 0.70710678118654752f));
      if (OP == OP_ADD) v += res[(size_t)r * N + c];
      C[(size_t)r * N + c] = v;
    }
  }
}

// ---------------- fused attention (one query per wave) ----------------
// qkv: (rowsBase.., 2304) rows = bgroup*Ntok + token; layout [3][NH][HD]
// out: (rows, 768) token-major, head-major within.
__global__ __launch_bounds__(256) void attn_kernel(
    const float* __restrict__ qkv, float* __restrict__ out,
    const float* __restrict__ relh, const float* __restrict__ relw,
    int Hd, int Wd) {
  const int Ntok = Hd * Wd;
  __shared__ float sc[4][1024];
  __shared__ float qs[4][64];
  __shared__ float bhs[4][32];
  __shared__ float bws[4][32];
  const int wave = threadIdx.x >> 6, lane = threadIdx.x & 63;
  const int bh = blockIdx.y;
  const int b = bh / NH, nh = bh % NH;
  const int qi = blockIdx.x * 4 + wave;
  const size_t base = ((size_t)b * Ntok) * 2304 + nh * 64;

  const float ql = qkv[base + (size_t)qi * 2304 + lane];
  qs[wave][lane] = ql;
  __syncthreads();

  const int qh = qi / Wd, qw = qi - qh * Wd;
  if (lane < Hd) {
    const float* rp = relh + (size_t)(qh - lane + Hd - 1) * 64;
    float s = 0.f;
#pragma unroll 16
    for (int c = 0; c < 64; c++) s += qs[wave][c] * rp[c];
    bhs[wave][lane] = s;
  }
  if (lane < Wd) {
    const float* rp = relw + (size_t)(qw - lane + Wd - 1) * 64;
    float s = 0.f;
#pragma unroll 16
    for (int c = 0; c < 64; c++) s += qs[wave][c] * rp[c];
    bws[wave][lane] = s;
  }
  __syncthreads();

  // scores for keys j = lane, lane+64, ...
  float m = -1e30f;
  int kh = lane / Wd;
  int kw = lane - kh * Wd;
  const float* kp = qkv + base + 768 + (size_t)lane * 2304;
  for (int j = lane; j < Ntok; j += 64) {
    float s = 0.f;
#pragma unroll 16
    for (int c = 0; c < 64; c++) s += qs[wave][c] * kp[c];
    s = s * 0.125f + bhs[wave][kh] + bws[wave][kw];
    sc[wave][j] = s;
    m = fmaxf(m, s);
    kp += (size_t)64 * 2304;
    kw += 64;
    while (kw >= Wd) { kw -= Wd; kh++; }
  }
#pragma unroll
  for (int off = 32; off; off >>= 1) m = fmaxf(m, __shfl_xor(m, off));

  float sum = 0.f;
  for (int j = lane; j < Ntok; j += 64) {
    float e = __expf(sc[wave][j] - m);
    sc[wave][j] = e;
    sum += e;
  }
#pragma unroll
  for (int off = 32; off; off >>= 1) sum += __shfl_xor(sum, off);
  __syncthreads();

  const float inv = 1.f / sum;
  const float* vp = qkv + base + 1536 + lane;
  float acc = 0.f;
  for (int j = 0; j < Ntok; j++) acc += sc[wave][j] * vp[(size_t)j * 2304];
  out[((size_t)b * Ntok + qi) * E + nh * 64 + lane] = acc * inv;
}

// ---------------- window partition / unpartition ----------------
__global__ __launch_bounds__(256) void win_part(const float* __restrict__ h,
                                                float* __restrict__ hw) {
  const int row = blockIdx.x;  // 0..3527
  const int win = row / NW, t = row - win * NW;
  const int wy = t / WS, wx = t - wy * WS;
  const int b = win / NWIN, wr = win - b * NWIN;
  const int by = wr / NWIN_SIDE, bx = wr - by * NWIN_SIDE;
  const int y = by * WS + wy, x = bx * WS + wx;
  float* dst = hw + (size_t)row * E;
  if (y < G && x < G) {
    const float* src = h + (((size_t)b * G + y) * G + x) * E;
    for (int e = threadIdx.x; e < E; e += 256) dst[e] = src[e];
  } else {
    for (int e = threadIdx.x; e < E; e += 256) dst[e] = 0.f;
  }
}

__global__ __launch_bounds__(256) void win_unpart(const float* __restrict__ aw,
                                                  float* __restrict__ ai) {
  const int row = blockIdx.x;  // 0..2047 : b*1024 + y*32 + x
  const int b = row >> 10, t = row & 1023, y = t >> 5, x = t & 31;
  const int by = y / WS, wy = y - by * WS;
  const int bx = x / WS, wx = x - bx * WS;
  const int win = b * NWIN + by * NWIN_SIDE + bx;
  const float* src = aw + ((size_t)win * NW + wy * WS + wx) * E;
  float* dst = ai + (size_t)row * E;
  for (int e = threadIdx.x; e < E; e += 256) dst[e] = src[e];
}

// ---------------- patch embed: conv16x16/s16 + patch_b + pos_embed ----------------
__global__ __launch_bounds__(256) void patch_embed(
    const float* __restrict__ x, const float* __restrict__ pw,
    const float* __restrict__ pb, const float* __restrict__ pos,
    float* __restrict__ out) {
  __shared__ float p[768];
  const int blk = blockIdx.x;  // b*1024 + gy*32 + gx
  const int b = blk >> 10, t = blk & 1023;
  const int gy = t >> 5, gx = t & 31;
  for (int k = threadIdx.x; k < 768; k += 256) {
    const int ci = k >> 8, rem = k & 255, py = rem >> 4, px = rem & 15;
    p[k] = x[(((size_t)b * 3 + ci) * 512 + gy * 16 + py) * 512 + gx * 16 + px];
  }
  __syncthreads();
  for (int o = threadIdx.x; o < 768; o += 256) {
    const float* wr = pw + (size_t)o * 768;
    float s = 0.f;
#pragma unroll 16
    for (int k = 0; k < 768; k++) s += p[k] * wr[k];
    out[(size_t)blk * E + o] = s + pb[o] + pos[(size_t)t * E + o];
  }
}

// ---------------- output head: einsum('bchw,oc->bohw') ----------------
__global__ __launch_bounds__(256) void head_kernel(
    const float* __restrict__ xb, const float* __restrict__ ow,
    const float* __restrict__ ob, float* __restrict__ out) {
  __shared__ float f[768];
  const int blk = blockIdx.x;  // b*1024 + gy*32 + gx
  const int b = blk >> 10, t = blk & 1023;
  for (int k = threadIdx.x; k < 768; k += 256) f[k] = xb[(size_t)blk * E + k];
  __syncthreads();
  const int o = threadIdx.x;  // 256 output channels
  const float* wr = ow + (size_t)o * 768;
  float s = 0.f;
#pragma unroll 16
  for (int k = 0; k < 768; k++) s += f[k] * wr[k];
  out[((size_t)b * 256 + o) * 1024 + t] = s + ob[o];
}

// ---------------- launch ----------------
extern "C" void kernel_launch(void* const* d_in, const int* in_sizes, int n_in,
                              void* d_out, int out_size, void* d_ws, size_t ws_size,
                              hipStream_t stream) {
  const float* x_in     = (const float*)d_in[0];
  const float* patch_w  = (const float*)d_in[1];
  const float* patch_b  = (const float*)d_in[2];
  const float* pos_emb  = (const float*)d_in[3];
  const float* ln1_w    = (const float*)d_in[4];
  const float* ln1_b    = (const float*)d_in[5];
  const float* qkv_w    = (const float*)d_in[6];
  const float* qkv_b    = (const float*)d_in[7];
  const float* proj_w   = (const float*)d_in[8];
  const float* proj_b   = (const float*)d_in[9];
  const float* rel_h_w  = (const float*)d_in[10];
  const float* rel_w_w  = (const float*)d_in[11];
  const float* rel_h_g  = (const float*)d_in[12];
  const float* rel_w_g  = (const float*)d_in[13];
  const float* ln2_w    = (const float*)d_in[14];
  const float* ln2_b    = (const float*)d_in[15];
  const float* fc1_w    = (const float*)d_in[16];
  const float* fc1_b    = (const float*)d_in[17];
  const float* fc2_w    = (const float*)d_in[18];
  const float* fc2_b    = (const float*)d_in[19];
  const float* out_w    = (const float*)d_in[20];
  const float* out_b    = (const float*)d_in[21];
  float* outp = (float*)d_out;

  float* ws = (float*)d_ws;
  float* xbuf   = ws;                        // 2048*768
  float* hbuf   = xbuf + (size_t)ROWS * E;   // 2048*768
  float* hwin   = hbuf + (size_t)ROWS * E;   // 3528*768
  float* qkvbuf = hwin + (size_t)WROWS * E;  // 3528*2304
  float* attnb  = qkvbuf + (size_t)WROWS * 3 * E;  // 3528*768
  float* aimg   = hwin;    // alias: windowed-h dead after qkv GEMM
  float* h1     = qkvbuf;  // alias: qkv dead during MLP (needs 2048*3072 <= 3528*2304)

  patch_embed<<<ROWS, 256, 0, stream>>>(x_in, patch_w, patch_b, pos_emb, xbuf);

  int win_i = 0, glob_i = 0;
  for (int i = 0; i < 12; i++) {
    const bool is_win = (WIN_MASK >> i) & 1;

    ln_kernel<<<ROWS, 256, 0, stream>>>(xbuf, ln1_w + i * E, ln1_b + i * E, hbuf);

    const float* attn_src;
    if (is_win) {
      win_part<<<WROWS, 256, 0, stream>>>(hbuf, hwin);
      gemm_kernel<OP_BIAS><<<dim3(3 * E / 64, (WROWS + 63) / 64), 256, 0, stream>>>(
          hwin, qkv_w + (size_t)i * E * 3 * E, qkv_b + i * 3 * E, nullptr,
          qkvbuf, WROWS, 3 * E, E);
      attn_kernel<<<dim3(NW / 4, BW * NH), 256, 0, stream>>>(
          qkvbuf, attnb, rel_h_w + (size_t)win_i * (2 * WS - 1) * HD,
          rel_w_w + (size_t)win_i * (2 * WS - 1) * HD, WS, WS);
      win_unpart<<<ROWS, 256, 0, stream>>>(attnb, aimg);
      attn_src = aimg;
      win_i++;
    } else {
      gemm_kernel<OP_BIAS><<<dim3(3 * E / 64, ROWS / 64), 256, 0, stream>>>(
          hbuf, qkv_w + (size_t)i * E * 3 * E, qkv_b + i * 3 * E, nullptr,
          qkvbuf, ROWS, 3 * E, E);
      attn_kernel<<<dim3(NTOK / 4, Bsz * NH), 256, 0, stream>>>(
          qkvbuf, attnb, rel_h_g + (size_t)glob_i * (2 * G - 1) * HD,
          rel_w_g + (size_t)glob_i * (2 * G - 1) * HD, G, G);
      attn_src = attnb;
      glob_i++;
    }

    // proj + residual -> xbuf
    gemm_kernel<OP_ADD><<<dim3(E / 64, ROWS / 64), 256, 0, stream>>>(
        attn_src, proj_w + (size_t)i * E * E, proj_b + i * E, xbuf,
        xbuf, ROWS, E, E);

    // MLP
    ln_kernel<<<ROWS, 256, 0, stream>>>(xbuf, ln2_w + i * E, ln2_b + i * E, hbuf);
    gemm_kernel<OP_GELU><<<dim3(4 * E / 64, ROWS / 64), 256, 0, stream>>>(
        hbuf, fc1_w + (size_t)i * E * 4 * E, fc1_b + i * 4 * E, nullptr,
        h1, ROWS, 4 * E, E);
    gemm_kernel<OP_ADD><<<dim3(E / 64, ROWS / 64), 256, 0, stream>>>(
        h1, fc2_w + (size_t)i * 4 * E * E, fc2_b + i * E, xbuf,
        xbuf, ROWS, E, 4 * E);
  }

  head_kernel<<<ROWS, 256, 0, stream>>>(xbuf, out_w, out_b, outp);
}

// Round 2
// 8064.819 us; speedup vs baseline: 1.9474x; 1.9474x over previous
//
#include <hip/hip_runtime.h>
#include <hip/hip_bf16.h>
#include <math.h>

// ---------------- constants ----------------
static constexpr int E   = 768;
static constexpr int NH  = 12;
static constexpr int HD  = 64;
static constexpr int Bsz = 2;
static constexpr int G   = 32;
static constexpr int NTOK = G * G;      // 1024
static constexpr int ROWS = Bsz * NTOK; // 2048
static constexpr int WS  = 14;
static constexpr int NWIN_SIDE = 3;
static constexpr int NWIN = NWIN_SIDE * NWIN_SIDE;
static constexpr int BW  = Bsz * NWIN;   // 18
static constexpr int NW  = WS * WS;      // 196
static constexpr int WROWS = BW * NW;    // 3528
static constexpr int WIN_MASK = 0x6DB;

typedef __attribute__((ext_vector_type(8))) short short8;
typedef __attribute__((ext_vector_type(4))) float f32x4;

__device__ __forceinline__ unsigned short f2bf(float x) {
  union { float f; unsigned u; } v; v.f = x;
  unsigned r = v.u + 0x7fffu + ((v.u >> 16) & 1u);
  return (unsigned short)(r >> 16);
}
__device__ __forceinline__ float bf2f(unsigned short h) {
  union { unsigned u; float f; } v; v.u = ((unsigned)h) << 16;
  return v.f;
}

// ---------------- LayerNorm (fp32) ----------------
__global__ __launch_bounds__(256) void ln_kernel(
    const float* __restrict__ in, const float* __restrict__ w,
    const float* __restrict__ b, float* __restrict__ out) {
  __shared__ float2 red[256];
  const int row = blockIdx.x, tid = threadIdx.x;
  const float* r = in + (size_t)row * E;
  float v0 = r[tid], v1 = r[tid + 256], v2 = r[tid + 512];
  float s = v0 + v1 + v2;
  float s2 = v0 * v0 + v1 * v1 + v2 * v2;
  red[tid] = make_float2(s, s2);
  __syncthreads();
  for (int off = 128; off; off >>= 1) {
    if (tid < off) {
      red[tid].x += red[tid + off].x;
      red[tid].y += red[tid + off].y;
    }
    __syncthreads();
  }
  const float mean = red[0].x * (1.f / E);
  const float var  = red[0].y * (1.f / E) - mean * mean;
  const float rs   = rsqrtf(var + 1e-6f);
  float* o = out + (size_t)row * E;
  o[tid]       = (v0 - mean) * rs * w[tid]       + b[tid];
  o[tid + 256] = (v1 - mean) * rs * w[tid + 256] + b[tid + 256];
  o[tid + 512] = (v2 - mean) * rs * w[tid + 512] + b[tid + 512];
}

// ---------------- MFMA bf16 GEMM: C = A(MxK) fp32 * B(KxN) fp32 ----------------
enum { OP_BIAS = 0, OP_GELU = 1, OP_ADD = 2 };

template <int OP>
__global__ __launch_bounds__(256) void gemm_mfma(
    const float* __restrict__ A, const float* __restrict__ Bm,
    const float* __restrict__ bias, const float* __restrict__ res,
    float* __restrict__ C, int M, int N, int K) {
  __shared__ unsigned short As[128][40];  // [row][k] pad->80B rows: 2-way max
  __shared__ unsigned short Bs[128][40];  // [col][k] transposed
  const int tid = threadIdx.x, wave = tid >> 6, lane = tid & 63;
  const int lx = lane & 15, ly = lane >> 4;
  const int row0 = blockIdx.y * 128, col0 = blockIdx.x * 128;
  const int wm = (wave >> 1) * 64, wn = (wave & 1) * 64;
  f32x4 acc[4][4] = {};

  for (int k0 = 0; k0 < K; k0 += 32) {
    __syncthreads();
    // A tile 128x32 fp32 -> bf16
#pragma unroll
    for (int i = 0; i < 4; i++) {
      int fv = i * 256 + tid;           // [128 rows][8 float4]
      int row = fv >> 3, kv = (fv & 7) * 4;
      float4 v = make_float4(0.f, 0.f, 0.f, 0.f);
      int gr = row0 + row;
      if (gr < M) v = *(const float4*)&A[(size_t)gr * K + k0 + kv];
      ushort4 p;
      p.x = f2bf(v.x); p.y = f2bf(v.y); p.z = f2bf(v.z); p.w = f2bf(v.w);
      *(ushort4*)&As[row][kv] = p;
    }
    // B tile 32x128 fp32 -> bf16 transposed
#pragma unroll
    for (int i = 0; i < 4; i++) {
      int fv = i * 256 + tid;           // [32 k][32 float4]
      int kr = fv >> 5, nv = (fv & 31) * 4;
      float4 v = *(const float4*)&Bm[(size_t)(k0 + kr) * N + col0 + nv];
      Bs[nv + 0][kr] = f2bf(v.x);
      Bs[nv + 1][kr] = f2bf(v.y);
      Bs[nv + 2][kr] = f2bf(v.z);
      Bs[nv + 3][kr] = f2bf(v.w);
    }
    __syncthreads();
    short8 af[4], bfr[4];
#pragma unroll
    for (int m = 0; m < 4; m++) af[m] = *(const short8*)&As[wm + m * 16 + lx][ly * 8];
#pragma unroll
    for (int n = 0; n < 4; n++) bfr[n] = *(const short8*)&Bs[wn + n * 16 + lx][ly * 8];
#pragma unroll
    for (int m = 0; m < 4; m++)
#pragma unroll
      for (int n = 0; n < 4; n++)
        acc[m][n] = __builtin_amdgcn_mfma_f32_16x16x32_bf16(af[m], bfr[n], acc[m][n], 0, 0, 0);
  }

#pragma unroll
  for (int m = 0; m < 4; m++) {
#pragma unroll
    for (int r = 0; r < 4; r++) {
      int gr = row0 + wm + m * 16 + ly * 4 + r;
      if (gr >= M) continue;
#pragma unroll
      for (int n = 0; n < 4; n++) {
        int gc = col0 + wn + n * 16 + lx;
        float v = acc[m][n][r] + bias[gc];
        if (OP == OP_GELU) v = 0.5f * v * (1.f + erff(v * 0.70710678118654752f));
        if (OP == OP_ADD) v += res[(size_t)gr * N + gc];
        C[(size_t)gr * N + gc] = v;
      }
    }
  }
}

// ---------------- MFMA flash attention with decomposed rel-pos ----------------
// qkv rows: bg*Ntok + token, cols [3][NH][64]. out rows same, cols nh*64+d.
__global__ __launch_bounds__(256) void attn_mfma(
    const float* __restrict__ qkv, float* __restrict__ out,
    const float* __restrict__ relh, const float* __restrict__ relw,
    int Hd, int Wd) {
  const int Ntok = Hd * Wd;
  __shared__ unsigned short Qs[64 * 64];   // XOR-swizzled, rows 128B
  __shared__ unsigned short Ks[32 * 64];   // XOR-swizzled
  __shared__ unsigned short Vst[64][40];   // [d][key] padded
  __shared__ unsigned short Ps[4][16][40]; // per-wave P, padded
  __shared__ float rhs[64][32];
  __shared__ float rws[64][32];
  const int tid = threadIdx.x, wave = tid >> 6, lane = tid & 63;
  const int lx = lane & 15, ly = lane >> 4;
  const int bh = blockIdx.y, b = bh / NH, nh = bh % NH;
  const int q0 = blockIdx.x * 64;
  const size_t base = (size_t)b * Ntok * 2304 + nh * 64;

  // ---- stage Q (64x64) ----
#pragma unroll
  for (int i = 0; i < 4; i++) {
    int fv = i * 256 + tid;
    int row = fv >> 4, dv = (fv & 15) * 4;
    int q = q0 + row;
    float4 v = make_float4(0.f, 0.f, 0.f, 0.f);
    if (q < Ntok) v = *(const float4*)&qkv[base + (size_t)q * 2304 + dv];
    ushort4 p;
    p.x = f2bf(v.x); p.y = f2bf(v.y); p.z = f2bf(v.z); p.w = f2bf(v.w);
    int idx = (row * 64 + dv) ^ ((row & 7) << 3);
    *(ushort4*)&Qs[idx] = p;
  }
  __syncthreads();

  // ---- rel-pos bias rows: rhs[q][kh], rws[q][kw] ----
  for (int p = tid; p < 64 * (Hd + Wd); p += 256) {
    int isw = (p >= 64 * Hd);
    int pp = isw ? p - 64 * Hd : p;
    int qrow = pp & 63, kk = pp >> 6;
    int q = q0 + qrow;
    int qc = (q < Ntok) ? q : (Ntok - 1);
    int qpos = isw ? (qc % Wd) : (qc / Wd);
    const float* rp = (isw ? relw : relh) + (size_t)(qpos - kk + (isw ? Wd : Hd) - 1) * 64;
    float acc = 0.f;
#pragma unroll 8
    for (int c = 0; c < 64; c++) {
      int idx = (qrow * 64 + c) ^ ((qrow & 7) << 3);
      acc += bf2f(Qs[idx]) * rp[c];
    }
    if (isw) rws[qrow][kk] = acc; else rhs[qrow][kk] = acc;
  }

  // ---- Q fragments (A-operand), kept in regs ----
  short8 qa[2];
  {
    int row = wave * 16 + lx;
#pragma unroll
    for (int kb = 0; kb < 2; kb++) {
      int idx = (row * 64 + kb * 32 + ly * 8) ^ ((row & 7) << 3);
      qa[kb] = *(const short8*)&Qs[idx];
    }
  }

  f32x4 o[4] = {};
  float mrow[4], lrow[4];
#pragma unroll
  for (int r = 0; r < 4; r++) { mrow[r] = -3e38f; lrow[r] = 0.f; }

  const int nkt = (Ntok + 31) >> 5;
  for (int kt = 0; kt < nkt; kt++) {
    __syncthreads();
    // ---- stage K (32x64) + V^T (64x32) ----
#pragma unroll
    for (int i = 0; i < 2; i++) {
      int fv = i * 256 + tid;
      int key = fv >> 4, dv = (fv & 15) * 4;
      int gk = kt * 32 + key;
      float4 kv = make_float4(0.f, 0.f, 0.f, 0.f);
      float4 vv = make_float4(0.f, 0.f, 0.f, 0.f);
      if (gk < Ntok) {
        kv = *(const float4*)&qkv[base + 768 + (size_t)gk * 2304 + dv];
        vv = *(const float4*)&qkv[base + 1536 + (size_t)gk * 2304 + dv];
      }
      ushort4 kp;
      kp.x = f2bf(kv.x); kp.y = f2bf(kv.y); kp.z = f2bf(kv.z); kp.w = f2bf(kv.w);
      int idx = (key * 64 + dv) ^ ((key & 7) << 3);
      *(ushort4*)&Ks[idx] = kp;
      Vst[dv + 0][key] = f2bf(vv.x);
      Vst[dv + 1][key] = f2bf(vv.y);
      Vst[dv + 2][key] = f2bf(vv.z);
      Vst[dv + 3][key] = f2bf(vv.w);
    }
    __syncthreads();

    // ---- QK^T: S tile 16(q) x 32(k) per wave ----
    f32x4 c[2] = {};
#pragma unroll
    for (int kb = 0; kb < 2; kb++) {
#pragma unroll
      for (int ct = 0; ct < 2; ct++) {
        int krow = ct * 16 + lx;
        int idx = (krow * 64 + kb * 32 + ly * 8) ^ ((krow & 7) << 3);
        short8 kf = *(const short8*)&Ks[idx];
        c[ct] = __builtin_amdgcn_mfma_f32_16x16x32_bf16(qa[kb], kf, c[ct], 0, 0, 0);
      }
    }

    // ---- online softmax update ----
    float pv0[4], pv1[4], mt[4];
#pragma unroll
    for (int r = 0; r < 4; r++) {
      int qrow = wave * 16 + ly * 4 + r;
      float s0 = c[0][r] * 0.125f, s1 = c[1][r] * 0.125f;
      int k0a = kt * 32 + lx, k1a = k0a + 16;
      if (k0a < Ntok) {
        int kh = k0a / Wd, kw = k0a - kh * Wd;
        s0 += rhs[qrow][kh] + rws[qrow][kw];
      } else s0 = -1e30f;
      if (k1a < Ntok) {
        int kh = k1a / Wd, kw = k1a - kh * Wd;
        s1 += rhs[qrow][kh] + rws[qrow][kw];
      } else s1 = -1e30f;
      pv0[r] = s0; pv1[r] = s1;
      mt[r] = fmaxf(s0, s1);
    }
#pragma unroll
    for (int off = 1; off <= 8; off <<= 1)
#pragma unroll
      for (int r = 0; r < 4; r++) mt[r] = fmaxf(mt[r], __shfl_xor(mt[r], off));
    float sc[4], lsum[4];
#pragma unroll
    for (int r = 0; r < 4; r++) {
      float mn = fmaxf(mrow[r], mt[r]);
      sc[r] = __expf(mrow[r] - mn);
      mrow[r] = mn;
      float p0 = __expf(pv0[r] - mn);
      float p1 = __expf(pv1[r] - mn);
      pv0[r] = p0; pv1[r] = p1;
      lsum[r] = p0 + p1;
    }
#pragma unroll
    for (int off = 1; off <= 8; off <<= 1)
#pragma unroll
      for (int r = 0; r < 4; r++) lsum[r] += __shfl_xor(lsum[r], off);
#pragma unroll
    for (int r = 0; r < 4; r++) lrow[r] = lrow[r] * sc[r] + lsum[r];
    // write P tile (bf16) — per-wave buffer, no cross-wave barrier needed
#pragma unroll
    for (int r = 0; r < 4; r++) {
      Ps[wave][ly * 4 + r][lx]      = f2bf(pv0[r]);
      Ps[wave][ly * 4 + r][16 + lx] = f2bf(pv1[r]);
    }
    // rescale O accumulators
#pragma unroll
    for (int dt = 0; dt < 4; dt++)
#pragma unroll
      for (int r = 0; r < 4; r++) o[dt][r] *= sc[r];
    // ---- PV ----
    short8 pf = *(const short8*)&Ps[wave][lx][ly * 8];
#pragma unroll
    for (int dt = 0; dt < 4; dt++) {
      short8 vf = *(const short8*)&Vst[dt * 16 + lx][ly * 8];
      o[dt] = __builtin_amdgcn_mfma_f32_16x16x32_bf16(pf, vf, o[dt], 0, 0, 0);
    }
  }

  // ---- store ----
#pragma unroll
  for (int r = 0; r < 4; r++) {
    int qrow = wave * 16 + ly * 4 + r;
    int q = q0 + qrow;
    if (q >= Ntok) continue;
    float inv = 1.f / lrow[r];
#pragma unroll
    for (int dt = 0; dt < 4; dt++)
      out[((size_t)b * Ntok + q) * E + nh * 64 + dt * 16 + lx] = o[dt][r] * inv;
  }
}

// ---------------- window partition / unpartition ----------------
__global__ __launch_bounds__(256) void win_part(const float* __restrict__ h,
                                                float* __restrict__ hw) {
  const int row = blockIdx.x;
  const int win = row / NW, t = row - win * NW;
  const int wy = t / WS, wx = t - wy * WS;
  const int b = win / NWIN, wr = win - b * NWIN;
  const int by = wr / NWIN_SIDE, bx = wr - by * NWIN_SIDE;
  const int y = by * WS + wy, x = bx * WS + wx;
  float* dst = hw + (size_t)row * E;
  if (y < G && x < G) {
    const float* src = h + (((size_t)b * G + y) * G + x) * E;
    for (int e = threadIdx.x; e < E; e += 256) dst[e] = src[e];
  } else {
    for (int e = threadIdx.x; e < E; e += 256) dst[e] = 0.f;
  }
}

__global__ __launch_bounds__(256) void win_unpart(const float* __restrict__ aw,
                                                  float* __restrict__ ai) {
  const int row = blockIdx.x;
  const int b = row >> 10, t = row & 1023, y = t >> 5, x = t & 31;
  const int by = y / WS, wy = y - by * WS;
  const int bx = x / WS, wx = x - bx * WS;
  const int win = b * NWIN + by * NWIN_SIDE + bx;
  const float* src = aw + ((size_t)win * NW + wy * WS + wx) * E;
  float* dst = ai + (size_t)row * E;
  for (int e = threadIdx.x; e < E; e += 256) dst[e] = src[e];
}

// ---------------- patch embed ----------------
__global__ __launch_bounds__(256) void patch_embed(
    const float* __restrict__ x, const float* __restrict__ pw,
    const float* __restrict__ pb, const float* __restrict__ pos,
    float* __restrict__ out) {
  __shared__ float p[768];
  const int blk = blockIdx.x;
  const int b = blk >> 10, t = blk & 1023;
  const int gy = t >> 5, gx = t & 31;
  for (int k = threadIdx.x; k < 768; k += 256) {
    const int ci = k >> 8, rem = k & 255, py = rem >> 4, px = rem & 15;
    p[k] = x[(((size_t)b * 3 + ci) * 512 + gy * 16 + py) * 512 + gx * 16 + px];
  }
  __syncthreads();
  for (int o = threadIdx.x; o < 768; o += 256) {
    const float* wr = pw + (size_t)o * 768;
    float s = 0.f;
#pragma unroll 16
    for (int k = 0; k < 768; k++) s += p[k] * wr[k];
    out[(size_t)blk * E + o] = s + pb[o] + pos[(size_t)t * E + o];
  }
}

// ---------------- output head ----------------
__global__ __launch_bounds__(256) void head_kernel(
    const float* __restrict__ xb, const float* __restrict__ ow,
    const float* __restrict__ ob, float* __restrict__ out) {
  __shared__ float f[768];
  const int blk = blockIdx.x;
  const int b = blk >> 10, t = blk & 1023;
  for (int k = threadIdx.x; k < 768; k += 256) f[k] = xb[(size_t)blk * E + k];
  __syncthreads();
  const int o = threadIdx.x;
  const float* wr = ow + (size_t)o * 768;
  float s = 0.f;
#pragma unroll 16
  for (int k = 0; k < 768; k++) s += f[k] * wr[k];
  out[((size_t)b * 256 + o) * 1024 + t] = s + ob[o];
}

// ---------------- launch ----------------
extern "C" void kernel_launch(void* const* d_in, const int* in_sizes, int n_in,
                              void* d_out, int out_size, void* d_ws, size_t ws_size,
                              hipStream_t stream) {
  const float* x_in     = (const float*)d_in[0];
  const float* patch_w  = (const float*)d_in[1];
  const float* patch_b  = (const float*)d_in[2];
  const float* pos_emb  = (const float*)d_in[3];
  const float* ln1_w    = (const float*)d_in[4];
  const float* ln1_b    = (const float*)d_in[5];
  const float* qkv_w    = (const float*)d_in[6];
  const float* qkv_b    = (const float*)d_in[7];
  const float* proj_w   = (const float*)d_in[8];
  const float* proj_b   = (const float*)d_in[9];
  const float* rel_h_w  = (const float*)d_in[10];
  const float* rel_w_w  = (const float*)d_in[11];
  const float* rel_h_g  = (const float*)d_in[12];
  const float* rel_w_g  = (const float*)d_in[13];
  const float* ln2_w    = (const float*)d_in[14];
  const float* ln2_b    = (const float*)d_in[15];
  const float* fc1_w    = (const float*)d_in[16];
  const float* fc1_b    = (const float*)d_in[17];
  const float* fc2_w    = (const float*)d_in[18];
  const float* fc2_b    = (const float*)d_in[19];
  const float* out_w    = (const float*)d_in[20];
  const float* out_b    = (const float*)d_in[21];
  float* outp = (float*)d_out;

  float* ws = (float*)d_ws;
  float* xbuf   = ws;                        // 2048*768
  float* hbuf   = xbuf + (size_t)ROWS * E;   // 2048*768
  float* hwin   = hbuf + (size_t)ROWS * E;   // 3528*768
  float* qkvbuf = hwin + (size_t)WROWS * E;  // 3528*2304
  float* attnb  = qkvbuf + (size_t)WROWS * 3 * E;  // 3528*768
  float* aimg   = hwin;    // alias
  float* h1     = qkvbuf;  // alias (2048*3072 <= 3528*2304)

  patch_embed<<<ROWS, 256, 0, stream>>>(x_in, patch_w, patch_b, pos_emb, xbuf);

  int win_i = 0, glob_i = 0;
  for (int i = 0; i < 12; i++) {
    const bool is_win = (WIN_MASK >> i) & 1;

    ln_kernel<<<ROWS, 256, 0, stream>>>(xbuf, ln1_w + i * E, ln1_b + i * E, hbuf);

    const float* attn_src;
    if (is_win) {
      win_part<<<WROWS, 256, 0, stream>>>(hbuf, hwin);
      gemm_mfma<OP_BIAS><<<dim3(3 * E / 128, (WROWS + 127) / 128), 256, 0, stream>>>(
          hwin, qkv_w + (size_t)i * E * 3 * E, qkv_b + i * 3 * E, nullptr,
          qkvbuf, WROWS, 3 * E, E);
      attn_mfma<<<dim3((NW + 63) / 64, BW * NH), 256, 0, stream>>>(
          qkvbuf, attnb, rel_h_w + (size_t)win_i * (2 * WS - 1) * HD,
          rel_w_w + (size_t)win_i * (2 * WS - 1) * HD, WS, WS);
      win_unpart<<<ROWS, 256, 0, stream>>>(attnb, aimg);
      attn_src = aimg;
      win_i++;
    } else {
      gemm_mfma<OP_BIAS><<<dim3(3 * E / 128, ROWS / 128), 256, 0, stream>>>(
          hbuf, qkv_w + (size_t)i * E * 3 * E, qkv_b + i * 3 * E, nullptr,
          qkvbuf, ROWS, 3 * E, E);
      attn_mfma<<<dim3(NTOK / 64, Bsz * NH), 256, 0, stream>>>(
          qkvbuf, attnb, rel_h_g + (size_t)glob_i * (2 * G - 1) * HD,
          rel_w_g + (size_t)glob_i * (2 * G - 1) * HD, G, G);
      attn_src = attnb;
      glob_i++;
    }

    gemm_mfma<OP_ADD><<<dim3(E / 128, ROWS / 128), 256, 0, stream>>>(
        attn_src, proj_w + (size_t)i * E * E, proj_b + i * E, xbuf,
        xbuf, ROWS, E, E);

    ln_kernel<<<ROWS, 256, 0, stream>>>(xbuf, ln2_w + i * E, ln2_b + i * E, hbuf);
    gemm_mfma<OP_GELU><<<dim3(4 * E / 128, ROWS / 128), 256, 0, stream>>>(
        hbuf, fc1_w + (size_t)i * E * 4 * E, fc1_b + i * 4 * E, nullptr,
        h1, ROWS, 4 * E, E);
    gemm_mfma<OP_ADD><<<dim3(E / 128, ROWS / 128), 256, 0, stream>>>(
        h1, fc2_w + (size_t)i * 4 * E * E, fc2_b + i * E, xbuf,
        xbuf, ROWS, E, 4 * E);
  }

  head_kernel<<<ROWS, 256, 0, stream>>>(xbuf, out_w, out_b, outp);
}

// Round 3
// 2965.828 us; speedup vs baseline: 5.2955x; 2.7192x over previous
//
#include <hip/hip_runtime.h>
#include <hip/hip_bf16.h>
#include <math.h>

// ---------------- constants ----------------
static constexpr int E   = 768;
static constexpr int NH  = 12;
static constexpr int HD  = 64;
static constexpr int Bsz = 2;
static constexpr int G   = 32;
static constexpr int NTOK = G * G;      // 1024
static constexpr int ROWS = Bsz * NTOK; // 2048
static constexpr int WS  = 14;
static constexpr int NWIN_SIDE = 3;
static constexpr int NWIN = NWIN_SIDE * NWIN_SIDE;
static constexpr int BW  = Bsz * NWIN;   // 18
static constexpr int NW  = WS * WS;      // 196
static constexpr int WROWS = BW * NW;    // 3528
static constexpr int WIN_MASK = 0x6DB;

typedef __attribute__((ext_vector_type(8))) short short8;
typedef __attribute__((ext_vector_type(4))) float f32x4;
typedef unsigned short ushort_t;

__device__ __forceinline__ unsigned short f2bf(float x) {
  union { float f; unsigned u; } v; v.f = x;
  unsigned r = v.u + 0x7fffu + ((v.u >> 16) & 1u);
  return (unsigned short)(r >> 16);
}
__device__ __forceinline__ float bf2f(unsigned short h) {
  union { unsigned u; float f; } v; v.u = ((unsigned)h) << 16;
  return v.f;
}

__device__ __forceinline__ void glds16(const void* g, void* l) {
  __builtin_amdgcn_global_load_lds(
      (const __attribute__((address_space(1))) unsigned*)g,
      (__attribute__((address_space(3))) unsigned*)l, 16, 0, 0);
}

// ---------------- LayerNorm fp32 -> bf16 ----------------
__global__ __launch_bounds__(256) void ln_kernel(
    const float* __restrict__ in, const float* __restrict__ w,
    const float* __restrict__ b, ushort_t* __restrict__ out) {
  __shared__ float2 red[256];
  const int row = blockIdx.x, tid = threadIdx.x;
  const float* r = in + (size_t)row * E;
  float v0 = r[tid], v1 = r[tid + 256], v2 = r[tid + 512];
  float s = v0 + v1 + v2;
  float s2 = v0 * v0 + v1 * v1 + v2 * v2;
  red[tid] = make_float2(s, s2);
  __syncthreads();
  for (int off = 128; off; off >>= 1) {
    if (tid < off) {
      red[tid].x += red[tid + off].x;
      red[tid].y += red[tid + off].y;
    }
    __syncthreads();
  }
  const float mean = red[0].x * (1.f / E);
  const float var  = red[0].y * (1.f / E) - mean * mean;
  const float rs   = rsqrtf(var + 1e-6f);
  ushort_t* o = out + (size_t)row * E;
  o[tid]       = f2bf((v0 - mean) * rs * w[tid]       + b[tid]);
  o[tid + 256] = f2bf((v1 - mean) * rs * w[tid + 256] + b[tid + 256]);
  o[tid + 512] = f2bf((v2 - mean) * rs * w[tid + 512] + b[tid + 512]);
}

// ---------------- bf16 GEMM, A(M,K) x Bt(N,K)^T, global_load_lds staged ----------------
enum { OP_QKV = 0, OP_GELU = 1, OP_ADD = 2, OP_POS = 3, OP_HEAD = 4 };

template <int OP>
__global__ __launch_bounds__(256) void gemm_bt(
    const ushort_t* __restrict__ A, const ushort_t* __restrict__ Bt,
    const float* __restrict__ bias, const float* __restrict__ res,
    const float* __restrict__ pos, void* __restrict__ Cp,
    int M, int N, int K) {
  __shared__ ushort_t As[128 * 64];
  __shared__ ushort_t Bs[128 * 64];
  const int tid = threadIdx.x, wave = tid >> 6, lane = tid & 63;
  const int lx = lane & 15, ly = lane >> 4;
  const int row0 = blockIdx.y * 128, col0 = blockIdx.x * 128;
  const int wm = (wave >> 1) * 64, wn = (wave & 1) * 64;
  const int rin = lane >> 3, pseg = lane & 7;
  const int lseg = pseg ^ rin;  // logical k-seg this lane fetches (swizzle src)
  f32x4 acc[4][4] = {};

  for (int k0 = 0; k0 < K; k0 += 64) {
    __syncthreads();
#pragma unroll
    for (int j = 0; j < 4; j++) {
      const int instr = wave * 4 + j;
      int ar = row0 + instr * 8 + rin;
      if (ar >= M) ar = M - 1;
      glds16(&A[(size_t)ar * K + k0 + lseg * 8], &As[instr * 512]);
      const int br = col0 + instr * 8 + rin;  // N is multiple of 128
      glds16(&Bt[(size_t)br * K + k0 + lseg * 8], &Bs[instr * 512]);
    }
    __syncthreads();
#pragma unroll
    for (int kb = 0; kb < 2; kb++) {
      short8 af[4], bfm[4];
#pragma unroll
      for (int m = 0; m < 4; m++) {
        const int r = wm + m * 16 + lx;
        af[m] = *(const short8*)&As[r * 64 + (((kb * 4 + ly) ^ (r & 7)) * 8)];
      }
#pragma unroll
      for (int n = 0; n < 4; n++) {
        const int r = wn + n * 16 + lx;
        bfm[n] = *(const short8*)&Bs[r * 64 + (((kb * 4 + ly) ^ (r & 7)) * 8)];
      }
#pragma unroll
      for (int m = 0; m < 4; m++)
#pragma unroll
        for (int n = 0; n < 4; n++)
          acc[m][n] = __builtin_amdgcn_mfma_f32_16x16x32_bf16(af[m], bfm[n], acc[m][n], 0, 0, 0);
    }
  }

#pragma unroll
  for (int m = 0; m < 4; m++) {
#pragma unroll
    for (int r4 = 0; r4 < 4; r4++) {
      const int gr = row0 + wm + m * 16 + ly * 4 + r4;
      if (gr >= M) continue;
#pragma unroll
      for (int n = 0; n < 4; n++) {
        const int gc = col0 + wn + n * 16 + lx;
        float v = acc[m][n][r4] + bias[gc];
        if (OP == OP_GELU) v = 0.5f * v * (1.f + erff(v * 0.70710678118654752f));
        if (OP == OP_ADD)  v += res[(size_t)gr * N + gc];
        if (OP == OP_POS)  v += pos[(size_t)(gr & 1023) * N + gc];
        if (OP == OP_QKV || OP == OP_GELU)
          ((ushort_t*)Cp)[(size_t)gr * N + gc] = f2bf(v);
        else if (OP == OP_HEAD)
          ((float*)Cp)[(((size_t)(gr >> 10) * 256 + gc) << 10) | (gr & 1023)] = v;
        else
          ((float*)Cp)[(size_t)gr * N + gc] = v;
      }
    }
  }
}

// ---------------- MFMA flash attention (bf16 qkv) ----------------
__global__ __launch_bounds__(256) void attn_mfma(
    const ushort_t* __restrict__ qkv, ushort_t* __restrict__ out,
    const float* __restrict__ relh, const float* __restrict__ relw,
    int Hd, int Wd) {
  const int Ntok = Hd * Wd;
  __shared__ ushort_t Qs[64 * 64];
  __shared__ ushort_t Ks[32 * 64];
  __shared__ ushort_t Vst[64][40];
  __shared__ ushort_t Ps[4][16][40];
  __shared__ float rhs[64][32];
  __shared__ float rws[64][32];
  const int tid = threadIdx.x, wave = tid >> 6, lane = tid & 63;
  const int lx = lane & 15, ly = lane >> 4;
  const int bh = blockIdx.y, b = bh / NH, nh = bh % NH;
  const int q0 = blockIdx.x * 64;
  const size_t base = (size_t)b * Ntok * 2304 + nh * 64;

  // stage Q (64x64), XOR-swizzled
#pragma unroll
  for (int i = 0; i < 2; i++) {
    const int fv = i * 256 + tid;
    const int row = fv >> 3, dv8 = (fv & 7) * 8;
    const int q = q0 + row;
    short8 v = {};
    if (q < Ntok) v = *(const short8*)&qkv[base + (size_t)q * 2304 + dv8];
    *(short8*)&Qs[(row * 64 + dv8) ^ ((row & 7) << 3)] = v;
  }
  __syncthreads();

  // rel-pos bias rows
  for (int p = tid; p < 64 * (Hd + Wd); p += 256) {
    const int isw = (p >= 64 * Hd);
    const int pp = isw ? p - 64 * Hd : p;
    const int qrow = pp & 63, kk = pp >> 6;
    const int q = q0 + qrow;
    const int qc = (q < Ntok) ? q : (Ntok - 1);
    const int qpos = isw ? (qc % Wd) : (qc / Wd);
    const float* rp = (isw ? relw : relh) + (size_t)(qpos - kk + (isw ? Wd : Hd) - 1) * 64;
    float acc = 0.f;
#pragma unroll 8
    for (int c = 0; c < 64; c++) {
      const int idx = (qrow * 64 + c) ^ ((qrow & 7) << 3);
      acc += bf2f(Qs[idx]) * rp[c];
    }
    if (isw) rws[qrow][kk] = acc; else rhs[qrow][kk] = acc;
  }

  // Q fragments
  short8 qa[2];
  {
    const int row = wave * 16 + lx;
#pragma unroll
    for (int kb = 0; kb < 2; kb++)
      qa[kb] = *(const short8*)&Qs[(row * 64 + kb * 32 + ly * 8) ^ ((row & 7) << 3)];
  }

  f32x4 o[4] = {};
  float mrow[4], lrow[4];
#pragma unroll
  for (int r = 0; r < 4; r++) { mrow[r] = -3e38f; lrow[r] = 0.f; }

  const int nkt = (Ntok + 31) >> 5;
  for (int kt = 0; kt < nkt; kt++) {
    __syncthreads();
    {
      const int row = tid >> 3, dv8 = (tid & 7) * 8;
      const int gk = kt * 32 + row;
      short8 kv = {}, vv = {};
      if (gk < Ntok) {
        kv = *(const short8*)&qkv[base + 768 + (size_t)gk * 2304 + dv8];
        vv = *(const short8*)&qkv[base + 1536 + (size_t)gk * 2304 + dv8];
      }
      *(short8*)&Ks[(row * 64 + dv8) ^ ((row & 7) << 3)] = kv;
#pragma unroll
      for (int j = 0; j < 8; j++) Vst[dv8 + j][row] = (ushort_t)vv[j];
    }
    __syncthreads();

    f32x4 c[2] = {};
#pragma unroll
    for (int kb = 0; kb < 2; kb++) {
#pragma unroll
      for (int ct = 0; ct < 2; ct++) {
        const int krow = ct * 16 + lx;
        short8 kf = *(const short8*)&Ks[(krow * 64 + kb * 32 + ly * 8) ^ ((krow & 7) << 3)];
        c[ct] = __builtin_amdgcn_mfma_f32_16x16x32_bf16(qa[kb], kf, c[ct], 0, 0, 0);
      }
    }

    float pv0[4], pv1[4], mt[4];
#pragma unroll
    for (int r = 0; r < 4; r++) {
      const int qrow = wave * 16 + ly * 4 + r;
      float s0 = c[0][r] * 0.125f, s1 = c[1][r] * 0.125f;
      const int k0a = kt * 32 + lx, k1a = k0a + 16;
      if (k0a < Ntok) {
        const int kh = k0a / Wd, kw = k0a - kh * Wd;
        s0 += rhs[qrow][kh] + rws[qrow][kw];
      } else s0 = -1e30f;
      if (k1a < Ntok) {
        const int kh = k1a / Wd, kw = k1a - kh * Wd;
        s1 += rhs[qrow][kh] + rws[qrow][kw];
      } else s1 = -1e30f;
      pv0[r] = s0; pv1[r] = s1;
      mt[r] = fmaxf(s0, s1);
    }
#pragma unroll
    for (int off = 1; off <= 8; off <<= 1)
#pragma unroll
      for (int r = 0; r < 4; r++) mt[r] = fmaxf(mt[r], __shfl_xor(mt[r], off));
    float scl[4], lsum[4];
#pragma unroll
    for (int r = 0; r < 4; r++) {
      const float mn = fmaxf(mrow[r], mt[r]);
      scl[r] = __expf(mrow[r] - mn);
      mrow[r] = mn;
      const float p0 = __expf(pv0[r] - mn);
      const float p1 = __expf(pv1[r] - mn);
      pv0[r] = p0; pv1[r] = p1;
      lsum[r] = p0 + p1;
    }
#pragma unroll
    for (int off = 1; off <= 8; off <<= 1)
#pragma unroll
      for (int r = 0; r < 4; r++) lsum[r] += __shfl_xor(lsum[r], off);
#pragma unroll
    for (int r = 0; r < 4; r++) lrow[r] = lrow[r] * scl[r] + lsum[r];
#pragma unroll
    for (int r = 0; r < 4; r++) {
      Ps[wave][ly * 4 + r][lx]      = f2bf(pv0[r]);
      Ps[wave][ly * 4 + r][16 + lx] = f2bf(pv1[r]);
    }
#pragma unroll
    for (int dt = 0; dt < 4; dt++)
#pragma unroll
      for (int r = 0; r < 4; r++) o[dt][r] *= scl[r];
    short8 pf = *(const short8*)&Ps[wave][lx][ly * 8];
#pragma unroll
    for (int dt = 0; dt < 4; dt++) {
      short8 vf = *(const short8*)&Vst[dt * 16 + lx][ly * 8];
      o[dt] = __builtin_amdgcn_mfma_f32_16x16x32_bf16(pf, vf, o[dt], 0, 0, 0);
    }
  }

#pragma unroll
  for (int r = 0; r < 4; r++) {
    const int qrow = wave * 16 + ly * 4 + r;
    const int q = q0 + qrow;
    if (q >= Ntok) continue;
    const float inv = 1.f / lrow[r];
#pragma unroll
    for (int dt = 0; dt < 4; dt++)
      out[((size_t)b * Ntok + q) * E + nh * 64 + dt * 16 + lx] = f2bf(o[dt][r] * inv);
  }
}

// ---------------- window partition / unpartition (bf16) ----------------
__global__ __launch_bounds__(128) void win_part(const ushort_t* __restrict__ h,
                                                ushort_t* __restrict__ hw) {
  const int row = blockIdx.x;
  const int win = row / NW, t = row - win * NW;
  const int wy = t / WS, wx = t - wy * WS;
  const int b = win / NWIN, wr = win - b * NWIN;
  const int by = wr / NWIN_SIDE, bx = wr - by * NWIN_SIDE;
  const int y = by * WS + wy, x = bx * WS + wx;
  short8* dst = (short8*)(hw + (size_t)row * E);
  if (y < G && x < G) {
    const short8* src = (const short8*)(h + (((size_t)b * G + y) * G + x) * E);
    for (int e = threadIdx.x; e < 96; e += 128) dst[e] = src[e];
  } else {
    short8 z = {};
    for (int e = threadIdx.x; e < 96; e += 128) dst[e] = z;
  }
}

__global__ __launch_bounds__(128) void win_unpart(const ushort_t* __restrict__ aw,
                                                  ushort_t* __restrict__ ai) {
  const int row = blockIdx.x;
  const int b = row >> 10, t = row & 1023, y = t >> 5, x = t & 31;
  const int by = y / WS, wy = y - by * WS;
  const int bx = x / WS, wx = x - bx * WS;
  const int win = b * NWIN + by * NWIN_SIDE + bx;
  const short8* src = (const short8*)(aw + ((size_t)win * NW + wy * WS + wx) * E);
  short8* dst = (short8*)(ai + (size_t)row * E);
  for (int e = threadIdx.x; e < 96; e += 128) dst[e] = src[e];
}

// ---------------- im2col: x(B,3,512,512) -> bf16 (2048, 768) ----------------
__global__ __launch_bounds__(256) void im2col(const float* __restrict__ x,
                                              ushort_t* __restrict__ out) {
  const int blk = blockIdx.x;
  const int b = blk >> 10, t = blk & 1023, gy = t >> 5, gx = t & 31;
  for (int k = threadIdx.x; k < 768; k += 256) {
    const int ci = k >> 8, rem = k & 255, py = rem >> 4, px = rem & 15;
    out[(size_t)blk * 768 + k] =
        f2bf(x[(((size_t)b * 3 + ci) * 512 + gy * 16 + py) * 512 + gx * 16 + px]);
  }
}

// ---------------- per-layer weight transpose fp32(K,N) -> bf16(N,K) ----------------
__global__ __launch_bounds__(256) void prep_wt(
    const float* __restrict__ qkvw, const float* __restrict__ projw,
    const float* __restrict__ fc1w, const float* __restrict__ fc2w,
    ushort_t* __restrict__ wq, ushort_t* __restrict__ wp,
    ushort_t* __restrict__ w1, ushort_t* __restrict__ w2) {
  __shared__ float tile[32][33];
  const int blk = blockIdx.x;
  const float* W; ushort_t* Wt; int Kd, Nd, tn, tk;
  if (blk < 1728)      { W = qkvw;  Wt = wq; Kd = 768;  Nd = 2304; tn = blk % 72;          tk = blk / 72; }
  else if (blk < 2304) { W = projw; Wt = wp; Kd = 768;  Nd = 768;  tn = (blk - 1728) % 24; tk = (blk - 1728) / 24; }
  else if (blk < 4608) { W = fc1w;  Wt = w1; Kd = 768;  Nd = 3072; tn = (blk - 2304) % 96; tk = (blk - 2304) / 96; }
  else                 { W = fc2w;  Wt = w2; Kd = 3072; Nd = 768;  tn = (blk - 4608) % 24; tk = (blk - 4608) / 24; }
  const int k0 = tk * 32, n0 = tn * 32;
  const int c = threadIdx.x & 31, r8 = threadIdx.x >> 5;
#pragma unroll
  for (int i = 0; i < 4; i++) {
    const int kr = i * 8 + r8;
    tile[kr][c] = W[(size_t)(k0 + kr) * Nd + n0 + c];
  }
  __syncthreads();
#pragma unroll
  for (int i = 0; i < 4; i++) {
    const int nr = i * 8 + r8;
    Wt[(size_t)(n0 + nr) * Kd + k0 + c] = f2bf(tile[c][nr]);
  }
}

// ---------------- elementwise fp32 -> bf16 ----------------
__global__ __launch_bounds__(256) void cast_bf16(const float* __restrict__ in,
                                                 ushort_t* __restrict__ out, int n) {
  const int idx = (blockIdx.x * 256 + threadIdx.x) * 4;
  if (idx + 3 < n) {
    const float4 v = *(const float4*)&in[idx];
    ushort4 p;
    p.x = f2bf(v.x); p.y = f2bf(v.y); p.z = f2bf(v.z); p.w = f2bf(v.w);
    *(ushort4*)&out[idx] = p;
  }
}

// ---------------- launch ----------------
extern "C" void kernel_launch(void* const* d_in, const int* in_sizes, int n_in,
                              void* d_out, int out_size, void* d_ws, size_t ws_size,
                              hipStream_t stream) {
  const float* x_in     = (const float*)d_in[0];
  const float* patch_w  = (const float*)d_in[1];
  const float* patch_b  = (const float*)d_in[2];
  const float* pos_emb  = (const float*)d_in[3];
  const float* ln1_w    = (const float*)d_in[4];
  const float* ln1_b    = (const float*)d_in[5];
  const float* qkv_w    = (const float*)d_in[6];
  const float* qkv_b    = (const float*)d_in[7];
  const float* proj_w   = (const float*)d_in[8];
  const float* proj_b   = (const float*)d_in[9];
  const float* rel_h_w  = (const float*)d_in[10];
  const float* rel_w_w  = (const float*)d_in[11];
  const float* rel_h_g  = (const float*)d_in[12];
  const float* rel_w_g  = (const float*)d_in[13];
  const float* ln2_w    = (const float*)d_in[14];
  const float* ln2_b    = (const float*)d_in[15];
  const float* fc1_w    = (const float*)d_in[16];
  const float* fc1_b    = (const float*)d_in[17];
  const float* fc2_w    = (const float*)d_in[18];
  const float* fc2_b    = (const float*)d_in[19];
  const float* out_w    = (const float*)d_in[20];
  const float* out_b    = (const float*)d_in[21];
  float* outp = (float*)d_out;

  // workspace layout
  float* xbuf = (float*)d_ws;                                   // 2048*768 f32
  ushort_t* hb16    = (ushort_t*)(xbuf + (size_t)ROWS * E);     // 2048*768
  ushort_t* hwin16  = hb16 + (size_t)ROWS * E;                  // 3528*768
  ushort_t* qkv16   = hwin16 + (size_t)WROWS * E;               // 3528*2304
  ushort_t* attnw16 = qkv16 + (size_t)WROWS * 3 * E;            // 3528*768
  ushort_t* wtbuf   = attnw16 + (size_t)WROWS * E;              // 7,077,888
  ushort_t* wq = wtbuf;                 // 2304*768
  ushort_t* wp = wq + 2304 * 768;       // 768*768
  ushort_t* w1 = wp + 768 * 768;        // 3072*768
  ushort_t* w2 = w1 + 3072 * 768;       // 768*3072
  ushort_t* imb16 = hb16;               // alias (patch phase only)
  ushort_t* aimg16 = hwin16;            // alias (hwin dead after qkv gemm)
  ushort_t* h1b16 = qkv16;              // alias (qkv dead during MLP)
  ushort_t* pwT16 = wtbuf;              // alias (before layer 0)
  ushort_t* headW16 = wtbuf;            // alias (after layer 11)

  // ---- patch embed as GEMM ----
  cast_bf16<<<576, 256, 0, stream>>>(patch_w, pwT16, 768 * 768);
  im2col<<<ROWS, 256, 0, stream>>>(x_in, imb16);
  gemm_bt<OP_POS><<<dim3(6, 16), 256, 0, stream>>>(
      imb16, pwT16, patch_b, nullptr, pos_emb, xbuf, ROWS, E, E);

  int win_i = 0, glob_i = 0;
  for (int i = 0; i < 12; i++) {
    const bool is_win = (WIN_MASK >> i) & 1;

    prep_wt<<<6912, 256, 0, stream>>>(
        qkv_w + (size_t)i * E * 3 * E, proj_w + (size_t)i * E * E,
        fc1_w + (size_t)i * E * 4 * E, fc2_w + (size_t)i * 4 * E * E,
        wq, wp, w1, w2);

    ln_kernel<<<ROWS, 256, 0, stream>>>(xbuf, ln1_w + i * E, ln1_b + i * E, hb16);

    const ushort_t* attn_src;
    if (is_win) {
      win_part<<<WROWS, 128, 0, stream>>>(hb16, hwin16);
      gemm_bt<OP_QKV><<<dim3(18, 28), 256, 0, stream>>>(
          hwin16, wq, qkv_b + i * 3 * E, nullptr, nullptr, qkv16, WROWS, 3 * E, E);
      attn_mfma<<<dim3(4, BW * NH), 256, 0, stream>>>(
          qkv16, attnw16, rel_h_w + (size_t)win_i * (2 * WS - 1) * HD,
          rel_w_w + (size_t)win_i * (2 * WS - 1) * HD, WS, WS);
      win_unpart<<<ROWS, 128, 0, stream>>>(attnw16, aimg16);
      attn_src = aimg16;
      win_i++;
    } else {
      gemm_bt<OP_QKV><<<dim3(18, 16), 256, 0, stream>>>(
          hb16, wq, qkv_b + i * 3 * E, nullptr, nullptr, qkv16, ROWS, 3 * E, E);
      attn_mfma<<<dim3(16, Bsz * NH), 256, 0, stream>>>(
          qkv16, attnw16, rel_h_g + (size_t)glob_i * (2 * G - 1) * HD,
          rel_w_g + (size_t)glob_i * (2 * G - 1) * HD, G, G);
      attn_src = attnw16;
      glob_i++;
    }

    gemm_bt<OP_ADD><<<dim3(6, 16), 256, 0, stream>>>(
        attn_src, wp, proj_b + i * E, xbuf, nullptr, xbuf, ROWS, E, E);

    ln_kernel<<<ROWS, 256, 0, stream>>>(xbuf, ln2_w + i * E, ln2_b + i * E, hb16);
    gemm_bt<OP_GELU><<<dim3(24, 16), 256, 0, stream>>>(
        hb16, w1, fc1_b + i * 4 * E, nullptr, nullptr, h1b16, ROWS, 4 * E, E);
    gemm_bt<OP_ADD><<<dim3(6, 16), 256, 0, stream>>>(
        h1b16, w2, fc2_b + i * E, xbuf, nullptr, xbuf, ROWS, E, 4 * E);
  }

  // ---- head ----
  cast_bf16<<<192, 256, 0, stream>>>(out_w, headW16, 256 * 768);
  cast_bf16<<<1536, 256, 0, stream>>>(xbuf, hb16, ROWS * E);
  gemm_bt<OP_HEAD><<<dim3(2, 16), 256, 0, stream>>>(
      hb16, headW16, out_b, nullptr, nullptr, outp, ROWS, 256, E);
}

// Round 4
// 2558.005 us; speedup vs baseline: 6.1398x; 1.1594x over previous
//
#include <hip/hip_runtime.h>
#include <hip/hip_bf16.h>
#include <math.h>

// ---------------- constants ----------------
static constexpr int E   = 768;
static constexpr int NH  = 12;
static constexpr int HD  = 64;
static constexpr int Bsz = 2;
static constexpr int G   = 32;
static constexpr int NTOK = G * G;      // 1024
static constexpr int ROWS = Bsz * NTOK; // 2048
static constexpr int WS  = 14;
static constexpr int NWIN_SIDE = 3;
static constexpr int NWIN = NWIN_SIDE * NWIN_SIDE;
static constexpr int BW  = Bsz * NWIN;   // 18
static constexpr int NW  = WS * WS;      // 196
static constexpr int WROWS = BW * NW;    // 3528
static constexpr int WIN_MASK = 0x6DB;

typedef __attribute__((ext_vector_type(8))) short short8;
typedef __attribute__((ext_vector_type(4))) float f32x4;
typedef unsigned short ushort_t;

__device__ __forceinline__ unsigned short f2bf(float x) {
  union { float f; unsigned u; } v; v.f = x;
  unsigned r = v.u + 0x7fffu + ((v.u >> 16) & 1u);
  return (unsigned short)(r >> 16);
}
__device__ __forceinline__ float bf2f(unsigned short h) {
  union { unsigned u; float f; } v; v.u = ((unsigned)h) << 16;
  return v.f;
}

__device__ __forceinline__ void glds16(const void* g, void* l) {
  __builtin_amdgcn_global_load_lds(
      (const __attribute__((address_space(1))) unsigned*)g,
      (__attribute__((address_space(3))) unsigned*)l, 16, 0, 0);
}

// ---------------- LayerNorm fp32 -> bf16, one wave per row ----------------
__global__ __launch_bounds__(256) void ln_kernel(
    const float* __restrict__ in, const float* __restrict__ w,
    const float* __restrict__ b, ushort_t* __restrict__ out) {
  const int wave = threadIdx.x >> 6, lane = threadIdx.x & 63;
  const int row = blockIdx.x * 4 + wave;
  const float4* r4 = (const float4*)(in + (size_t)row * E);
  float4 v[3];
  v[0] = r4[lane]; v[1] = r4[lane + 64]; v[2] = r4[lane + 128];
  float s = 0.f, s2 = 0.f;
#pragma unroll
  for (int i = 0; i < 3; i++) {
    s += v[i].x + v[i].y + v[i].z + v[i].w;
    s2 += v[i].x * v[i].x + v[i].y * v[i].y + v[i].z * v[i].z + v[i].w * v[i].w;
  }
#pragma unroll
  for (int off = 1; off <= 32; off <<= 1) {
    s += __shfl_xor(s, off);
    s2 += __shfl_xor(s2, off);
  }
  const float mean = s * (1.f / E);
  const float var  = s2 * (1.f / E) - mean * mean;
  const float rs   = rsqrtf(var + 1e-6f);
  ushort_t* o = out + (size_t)row * E;
#pragma unroll
  for (int i = 0; i < 3; i++) {
    const int e0 = (lane + i * 64) * 4;
    ushort4 p;
    p.x = f2bf((v[i].x - mean) * rs * w[e0]     + b[e0]);
    p.y = f2bf((v[i].y - mean) * rs * w[e0 + 1] + b[e0 + 1]);
    p.z = f2bf((v[i].z - mean) * rs * w[e0 + 2] + b[e0 + 2]);
    p.w = f2bf((v[i].w - mean) * rs * w[e0 + 3] + b[e0 + 3]);
    *(ushort4*)&o[e0] = p;
  }
}

// ---------------- bf16 GEMM, A(M,K) x Bt(N,K)^T, global_load_lds staged ----------------
enum { OP_QKV = 0, OP_GELU = 1, OP_ADD = 2, OP_POS = 3, OP_HEAD = 4 };

template <int OP>
__global__ __launch_bounds__(256) void gemm_bt(
    const ushort_t* __restrict__ A, const ushort_t* __restrict__ Bt,
    const float* __restrict__ bias, const float* __restrict__ res,
    const float* __restrict__ pos, void* __restrict__ Cp,
    int M, int N, int K) {
  __shared__ ushort_t As[128 * 64];
  __shared__ ushort_t Bs[128 * 64];
  const int tid = threadIdx.x, wave = tid >> 6, lane = tid & 63;
  const int lx = lane & 15, ly = lane >> 4;
  const int row0 = blockIdx.y * 128, col0 = blockIdx.x * 128;
  const int wm = (wave >> 1) * 64, wn = (wave & 1) * 64;
  const int rin = lane >> 3, pseg = lane & 7;
  const int lseg = pseg ^ rin;
  f32x4 acc[4][4] = {};

  for (int k0 = 0; k0 < K; k0 += 64) {
    __syncthreads();
#pragma unroll
    for (int j = 0; j < 4; j++) {
      const int instr = wave * 4 + j;
      int ar = row0 + instr * 8 + rin;
      if (ar >= M) ar = M - 1;
      glds16(&A[(size_t)ar * K + k0 + lseg * 8], &As[instr * 512]);
      const int br = col0 + instr * 8 + rin;
      glds16(&Bt[(size_t)br * K + k0 + lseg * 8], &Bs[instr * 512]);
    }
    __syncthreads();
#pragma unroll
    for (int kb = 0; kb < 2; kb++) {
      short8 af[4], bfm[4];
#pragma unroll
      for (int m = 0; m < 4; m++) {
        const int r = wm + m * 16 + lx;
        af[m] = *(const short8*)&As[r * 64 + (((kb * 4 + ly) ^ (r & 7)) * 8)];
      }
#pragma unroll
      for (int n = 0; n < 4; n++) {
        const int r = wn + n * 16 + lx;
        bfm[n] = *(const short8*)&Bs[r * 64 + (((kb * 4 + ly) ^ (r & 7)) * 8)];
      }
#pragma unroll
      for (int m = 0; m < 4; m++)
#pragma unroll
        for (int n = 0; n < 4; n++)
          acc[m][n] = __builtin_amdgcn_mfma_f32_16x16x32_bf16(af[m], bfm[n], acc[m][n], 0, 0, 0);
    }
  }

#pragma unroll
  for (int m = 0; m < 4; m++) {
#pragma unroll
    for (int r4 = 0; r4 < 4; r4++) {
      const int gr = row0 + wm + m * 16 + ly * 4 + r4;
      if (gr >= M) continue;
#pragma unroll
      for (int n = 0; n < 4; n++) {
        const int gc = col0 + wn + n * 16 + lx;
        float v = acc[m][n][r4] + bias[gc];
        if (OP == OP_GELU) v = 0.5f * v * (1.f + erff(v * 0.70710678118654752f));
        if (OP == OP_ADD)  v += res[(size_t)gr * N + gc];
        if (OP == OP_POS)  v += pos[(size_t)(gr & 1023) * N + gc];
        if (OP == OP_QKV || OP == OP_GELU)
          ((ushort_t*)Cp)[(size_t)gr * N + gc] = f2bf(v);
        else if (OP == OP_HEAD)
          ((float*)Cp)[(((size_t)(gr >> 10) * 256 + gc) << 10) | (gr & 1023)] = v;
        else
          ((float*)Cp)[(size_t)gr * N + gc] = v;
      }
    }
  }
}

// ---------------- MFMA flash attention, rel-pos bias via MFMA T-tables ----------------
__global__ __launch_bounds__(256) void attn_mfma(
    const ushort_t* __restrict__ qkv, ushort_t* __restrict__ out,
    const float* __restrict__ relh, const float* __restrict__ relw,
    int Hd, int Wd) {
  const int Ntok = Hd * Wd;
  __shared__ ushort_t smem[20736];
  ushort_t* Qs   = smem;                                   // [64*64] swizzled
  ushort_t* RelS = smem + 4096;                            // prologue alias
  ushort_t* Ks   = smem + 4096;                            // [32*64] swizzled
  ushort_t (*Vst)[40] = (ushort_t(*)[40])(smem + 6144);    // [64][40]
  ushort_t (*Ps)[16][40] = (ushort_t(*)[16][40])(smem + 8704);  // [4][16][40]
  ushort_t (*Th)[66] = (ushort_t(*)[66])(smem + 11264);    // [64][66]
  ushort_t (*Tw)[66] = (ushort_t(*)[66])(smem + 15488);    // [64][66]
  ushort_t* khw = smem + 19712;                            // [1024]

  const int tid = threadIdx.x, wave = tid >> 6, lane = tid & 63;
  const int lx = lane & 15, ly = lane >> 4;
  const int bh = blockIdx.y, b = bh / NH, nh = bh % NH;
  const int q0 = blockIdx.x * 64;
  const size_t base = (size_t)b * Ntok * 2304 + nh * 64;

  // ---- stage Q (64x64) swizzled + khw table ----
#pragma unroll
  for (int i = 0; i < 2; i++) {
    const int fv = i * 256 + tid;
    const int row = fv >> 3, dv8 = (fv & 7) * 8;
    const int q = q0 + row;
    short8 v = {};
    if (q < Ntok) v = *(const short8*)&qkv[base + (size_t)q * 2304 + dv8];
    *(short8*)&Qs[(row * 64 + dv8) ^ ((row & 7) << 3)] = v;
  }
  for (int k = tid; k < 1024; k += 256) {
    const int kc = min(k, Ntok - 1);
    const int kh = kc / Wd;
    const int kw = kc - kh * Wd;
    khw[k] = (ushort_t)((kh << 8) | kw);
  }
  __syncthreads();

  // ---- Q fragments ----
  short8 qa[2];
  {
    const int row = wave * 16 + lx;
#pragma unroll
    for (int kb = 0; kb < 2; kb++)
      qa[kb] = *(const short8*)&Qs[(row * 64 + kb * 32 + ly * 8) ^ ((row & 7) << 3)];
  }

  // ---- per-row q coords ----
  int qh_r[4], qw_r[4];
#pragma unroll
  for (int r = 0; r < 4; r++) {
    const int q = q0 + wave * 16 + ly * 4 + r;
    const int qc = min(q, Ntok - 1);
    qh_r[r] = qc / Wd;
    qw_r[r] = qc - qh_r[r] * Wd;
  }

  // ---- T tables via MFMA: T[q][j] = dot(Q[q], rel[j]) ----
  for (int t = 0; t < 2; t++) {
    const float* rel = t ? relw : relh;
    const int TR = t ? (2 * Wd - 1) : (2 * Hd - 1);
    __syncthreads();
#pragma unroll
    for (int i = 0; i < 2; i++) {
      const int fv = i * 256 + tid;
      const int row = fv >> 3, c8 = (fv & 7) * 8;
      short8 v = {};
      if (row < TR) {
        const float* rp = &rel[(size_t)row * 64 + c8];
        const float4 a = *(const float4*)rp;
        const float4 bq = *(const float4*)(rp + 4);
        v[0] = (short)f2bf(a.x);  v[1] = (short)f2bf(a.y);
        v[2] = (short)f2bf(a.z);  v[3] = (short)f2bf(a.w);
        v[4] = (short)f2bf(bq.x); v[5] = (short)f2bf(bq.y);
        v[6] = (short)f2bf(bq.z); v[7] = (short)f2bf(bq.w);
      }
      *(short8*)&RelS[(row * 64 + c8) ^ ((row & 7) << 3)] = v;
    }
    __syncthreads();
    const int NT = (TR + 15) >> 4;
    ushort_t (*T)[66] = t ? Tw : Th;
    for (int nt = 0; nt < NT; nt++) {
      f32x4 a = {};
      __builtin_amdgcn_s_setprio(1);
#pragma unroll
      for (int kb = 0; kb < 2; kb++) {
        const int rrow = nt * 16 + lx;
        short8 bf = *(const short8*)&RelS[(rrow * 64 + kb * 32 + ly * 8) ^ ((rrow & 7) << 3)];
        a = __builtin_amdgcn_mfma_f32_16x16x32_bf16(qa[kb], bf, a, 0, 0, 0);
      }
      __builtin_amdgcn_s_setprio(0);
#pragma unroll
      for (int reg = 0; reg < 4; reg++)
        T[wave * 16 + ly * 4 + reg][nt * 16 + lx] = f2bf(a[reg]);
    }
  }

  f32x4 o[4] = {};
  float mrow[4], lrow[4];
#pragma unroll
  for (int r = 0; r < 4; r++) { mrow[r] = -3e38f; lrow[r] = 0.f; }

  const int nkt = (Ntok + 31) >> 5;
  for (int kt = 0; kt < nkt; kt++) {
    __syncthreads();
    {
      const int row = tid >> 3, dv8 = (tid & 7) * 8;
      const int gk = kt * 32 + row;
      short8 kv = {}, vv = {};
      if (gk < Ntok) {
        kv = *(const short8*)&qkv[base + 768 + (size_t)gk * 2304 + dv8];
        vv = *(const short8*)&qkv[base + 1536 + (size_t)gk * 2304 + dv8];
      }
      *(short8*)&Ks[(row * 64 + dv8) ^ ((row & 7) << 3)] = kv;
#pragma unroll
      for (int j = 0; j < 8; j++) Vst[dv8 + j][row] = (ushort_t)vv[j];
    }
    __syncthreads();

    f32x4 c[2] = {};
    __builtin_amdgcn_s_setprio(1);
#pragma unroll
    for (int kb = 0; kb < 2; kb++) {
#pragma unroll
      for (int ct = 0; ct < 2; ct++) {
        const int krow = ct * 16 + lx;
        short8 kf = *(const short8*)&Ks[(krow * 64 + kb * 32 + ly * 8) ^ ((krow & 7) << 3)];
        c[ct] = __builtin_amdgcn_mfma_f32_16x16x32_bf16(qa[kb], kf, c[ct], 0, 0, 0);
      }
    }
    __builtin_amdgcn_s_setprio(0);

    // bias lookup (T tables) + mask
    const int k0a = kt * 32 + lx, k1a = k0a + 16;
    const int tv0 = khw[min(k0a, 1023)], tv1 = khw[min(k1a, 1023)];
    const int kh0 = tv0 >> 8, kw0 = tv0 & 255;
    const int kh1 = tv1 >> 8, kw1 = tv1 & 255;
    float pv0[4], pv1[4], mt[4];
#pragma unroll
    for (int r = 0; r < 4; r++) {
      const int qrow = wave * 16 + ly * 4 + r;
      float s0 = c[0][r] * 0.125f, s1 = c[1][r] * 0.125f;
      s0 += bf2f(Th[qrow][qh_r[r] - kh0 + Hd - 1]) + bf2f(Tw[qrow][qw_r[r] - kw0 + Wd - 1]);
      s1 += bf2f(Th[qrow][qh_r[r] - kh1 + Hd - 1]) + bf2f(Tw[qrow][qw_r[r] - kw1 + Wd - 1]);
      if (k0a >= Ntok) s0 = -1e30f;
      if (k1a >= Ntok) s1 = -1e30f;
      pv0[r] = s0; pv1[r] = s1;
      mt[r] = fmaxf(s0, s1);
    }
#pragma unroll
    for (int off = 1; off <= 8; off <<= 1)
#pragma unroll
      for (int r = 0; r < 4; r++) mt[r] = fmaxf(mt[r], __shfl_xor(mt[r], off));
    float scl[4], lsum[4];
#pragma unroll
    for (int r = 0; r < 4; r++) {
      const float mn = fmaxf(mrow[r], mt[r]);
      scl[r] = __expf(mrow[r] - mn);
      mrow[r] = mn;
      const float p0 = __expf(pv0[r] - mn);
      const float p1 = __expf(pv1[r] - mn);
      pv0[r] = p0; pv1[r] = p1;
      lsum[r] = p0 + p1;
    }
#pragma unroll
    for (int off = 1; off <= 8; off <<= 1)
#pragma unroll
      for (int r = 0; r < 4; r++) lsum[r] += __shfl_xor(lsum[r], off);
#pragma unroll
    for (int r = 0; r < 4; r++) lrow[r] = lrow[r] * scl[r] + lsum[r];
#pragma unroll
    for (int r = 0; r < 4; r++) {
      Ps[wave][ly * 4 + r][lx]      = f2bf(pv0[r]);
      Ps[wave][ly * 4 + r][16 + lx] = f2bf(pv1[r]);
    }
#pragma unroll
    for (int dt = 0; dt < 4; dt++)
#pragma unroll
      for (int r = 0; r < 4; r++) o[dt][r] *= scl[r];
    short8 pf = *(const short8*)&Ps[wave][lx][ly * 8];
    __builtin_amdgcn_s_setprio(1);
#pragma unroll
    for (int dt = 0; dt < 4; dt++) {
      short8 vf = *(const short8*)&Vst[dt * 16 + lx][ly * 8];
      o[dt] = __builtin_amdgcn_mfma_f32_16x16x32_bf16(pf, vf, o[dt], 0, 0, 0);
    }
    __builtin_amdgcn_s_setprio(0);
  }

#pragma unroll
  for (int r = 0; r < 4; r++) {
    const int qrow = wave * 16 + ly * 4 + r;
    const int q = q0 + qrow;
    if (q >= Ntok) continue;
    const float inv = 1.f / lrow[r];
#pragma unroll
    for (int dt = 0; dt < 4; dt++)
      out[((size_t)b * Ntok + q) * E + nh * 64 + dt * 16 + lx] = f2bf(o[dt][r] * inv);
  }
}

// ---------------- window partition / unpartition (bf16) ----------------
__global__ __launch_bounds__(128) void win_part(const ushort_t* __restrict__ h,
                                                ushort_t* __restrict__ hw) {
  const int row = blockIdx.x;
  const int win = row / NW, t = row - win * NW;
  const int wy = t / WS, wx = t - wy * WS;
  const int b = win / NWIN, wr = win - b * NWIN;
  const int by = wr / NWIN_SIDE, bx = wr - by * NWIN_SIDE;
  const int y = by * WS + wy, x = bx * WS + wx;
  short8* dst = (short8*)(hw + (size_t)row * E);
  if (y < G && x < G) {
    const short8* src = (const short8*)(h + (((size_t)b * G + y) * G + x) * E);
    for (int e = threadIdx.x; e < 96; e += 128) dst[e] = src[e];
  } else {
    short8 z = {};
    for (int e = threadIdx.x; e < 96; e += 128) dst[e] = z;
  }
}

__global__ __launch_bounds__(128) void win_unpart(const ushort_t* __restrict__ aw,
                                                  ushort_t* __restrict__ ai) {
  const int row = blockIdx.x;
  const int b = row >> 10, t = row & 1023, y = t >> 5, x = t & 31;
  const int by = y / WS, wy = y - by * WS;
  const int bx = x / WS, wx = x - bx * WS;
  const int win = b * NWIN + by * NWIN_SIDE + bx;
  const short8* src = (const short8*)(aw + ((size_t)win * NW + wy * WS + wx) * E);
  short8* dst = (short8*)(ai + (size_t)row * E);
  for (int e = threadIdx.x; e < 96; e += 128) dst[e] = src[e];
}

// ---------------- im2col ----------------
__global__ __launch_bounds__(256) void im2col(const float* __restrict__ x,
                                              ushort_t* __restrict__ out) {
  const int blk = blockIdx.x;
  const int b = blk >> 10, t = blk & 1023, gy = t >> 5, gx = t & 31;
  for (int k = threadIdx.x; k < 768; k += 256) {
    const int ci = k >> 8, rem = k & 255, py = rem >> 4, px = rem & 15;
    out[(size_t)blk * 768 + k] =
        f2bf(x[(((size_t)b * 3 + ci) * 512 + gy * 16 + py) * 512 + gx * 16 + px]);
  }
}

// ---------------- per-layer weight transpose fp32(K,N) -> bf16(N,K) ----------------
__global__ __launch_bounds__(256) void prep_wt(
    const float* __restrict__ qkvw, const float* __restrict__ projw,
    const float* __restrict__ fc1w, const float* __restrict__ fc2w,
    ushort_t* __restrict__ wq, ushort_t* __restrict__ wp,
    ushort_t* __restrict__ w1, ushort_t* __restrict__ w2) {
  __shared__ float tile[32][33];
  const int blk = blockIdx.x;
  const float* W; ushort_t* Wt; int Kd, Nd, tn, tk;
  if (blk < 1728)      { W = qkvw;  Wt = wq; Kd = 768;  Nd = 2304; tn = blk % 72;          tk = blk / 72; }
  else if (blk < 2304) { W = projw; Wt = wp; Kd = 768;  Nd = 768;  tn = (blk - 1728) % 24; tk = (blk - 1728) / 24; }
  else if (blk < 4608) { W = fc1w;  Wt = w1; Kd = 768;  Nd = 3072; tn = (blk - 2304) % 96; tk = (blk - 2304) / 96; }
  else                 { W = fc2w;  Wt = w2; Kd = 3072; Nd = 768;  tn = (blk - 4608) % 24; tk = (blk - 4608) / 24; }
  const int k0 = tk * 32, n0 = tn * 32;
  const int c = threadIdx.x & 31, r8 = threadIdx.x >> 5;
#pragma unroll
  for (int i = 0; i < 4; i++) {
    const int kr = i * 8 + r8;
    tile[kr][c] = W[(size_t)(k0 + kr) * Nd + n0 + c];
  }
  __syncthreads();
#pragma unroll
  for (int i = 0; i < 4; i++) {
    const int nr = i * 8 + r8;
    Wt[(size_t)(n0 + nr) * Kd + k0 + c] = f2bf(tile[c][nr]);
  }
}

// ---------------- elementwise fp32 -> bf16 ----------------
__global__ __launch_bounds__(256) void cast_bf16(const float* __restrict__ in,
                                                 ushort_t* __restrict__ out, int n) {
  const int idx = (blockIdx.x * 256 + threadIdx.x) * 4;
  if (idx + 3 < n) {
    const float4 v = *(const float4*)&in[idx];
    ushort4 p;
    p.x = f2bf(v.x); p.y = f2bf(v.y); p.z = f2bf(v.z); p.w = f2bf(v.w);
    *(ushort4*)&out[idx] = p;
  }
}

// ---------------- launch ----------------
extern "C" void kernel_launch(void* const* d_in, const int* in_sizes, int n_in,
                              void* d_out, int out_size, void* d_ws, size_t ws_size,
                              hipStream_t stream) {
  const float* x_in     = (const float*)d_in[0];
  const float* patch_w  = (const float*)d_in[1];
  const float* patch_b  = (const float*)d_in[2];
  const float* pos_emb  = (const float*)d_in[3];
  const float* ln1_w    = (const float*)d_in[4];
  const float* ln1_b    = (const float*)d_in[5];
  const float* qkv_w    = (const float*)d_in[6];
  const float* qkv_b    = (const float*)d_in[7];
  const float* proj_w   = (const float*)d_in[8];
  const float* proj_b   = (const float*)d_in[9];
  const float* rel_h_w  = (const float*)d_in[10];
  const float* rel_w_w  = (const float*)d_in[11];
  const float* rel_h_g  = (const float*)d_in[12];
  const float* rel_w_g  = (const float*)d_in[13];
  const float* ln2_w    = (const float*)d_in[14];
  const float* ln2_b    = (const float*)d_in[15];
  const float* fc1_w    = (const float*)d_in[16];
  const float* fc1_b    = (const float*)d_in[17];
  const float* fc2_w    = (const float*)d_in[18];
  const float* fc2_b    = (const float*)d_in[19];
  const float* out_w    = (const float*)d_in[20];
  const float* out_b    = (const float*)d_in[21];
  float* outp = (float*)d_out;

  float* xbuf = (float*)d_ws;                                   // 2048*768 f32
  ushort_t* hb16    = (ushort_t*)(xbuf + (size_t)ROWS * E);     // 2048*768
  ushort_t* hwin16  = hb16 + (size_t)ROWS * E;                  // 3528*768
  ushort_t* qkv16   = hwin16 + (size_t)WROWS * E;               // 3528*2304
  ushort_t* attnw16 = qkv16 + (size_t)WROWS * 3 * E;            // 3528*768
  ushort_t* wtbuf   = attnw16 + (size_t)WROWS * E;
  ushort_t* wq = wtbuf;                 // 2304*768
  ushort_t* wp = wq + 2304 * 768;       // 768*768
  ushort_t* w1 = wp + 768 * 768;        // 3072*768
  ushort_t* w2 = w1 + 3072 * 768;       // 768*3072
  ushort_t* imb16 = hb16;
  ushort_t* aimg16 = hwin16;
  ushort_t* h1b16 = qkv16;
  ushort_t* pwT16 = wtbuf;
  ushort_t* headW16 = wtbuf;

  // ---- patch embed as GEMM ----
  cast_bf16<<<576, 256, 0, stream>>>(patch_w, pwT16, 768 * 768);
  im2col<<<ROWS, 256, 0, stream>>>(x_in, imb16);
  gemm_bt<OP_POS><<<dim3(6, 16), 256, 0, stream>>>(
      imb16, pwT16, patch_b, nullptr, pos_emb, xbuf, ROWS, E, E);

  int win_i = 0, glob_i = 0;
  for (int i = 0; i < 12; i++) {
    const bool is_win = (WIN_MASK >> i) & 1;

    prep_wt<<<6912, 256, 0, stream>>>(
        qkv_w + (size_t)i * E * 3 * E, proj_w + (size_t)i * E * E,
        fc1_w + (size_t)i * E * 4 * E, fc2_w + (size_t)i * 4 * E * E,
        wq, wp, w1, w2);

    ln_kernel<<<ROWS / 4, 256, 0, stream>>>(xbuf, ln1_w + i * E, ln1_b + i * E, hb16);

    const ushort_t* attn_src;
    if (is_win) {
      win_part<<<WROWS, 128, 0, stream>>>(hb16, hwin16);
      gemm_bt<OP_QKV><<<dim3(18, 28), 256, 0, stream>>>(
          hwin16, wq, qkv_b + i * 3 * E, nullptr, nullptr, qkv16, WROWS, 3 * E, E);
      attn_mfma<<<dim3(4, BW * NH), 256, 0, stream>>>(
          qkv16, attnw16, rel_h_w + (size_t)win_i * (2 * WS - 1) * HD,
          rel_w_w + (size_t)win_i * (2 * WS - 1) * HD, WS, WS);
      win_unpart<<<ROWS, 128, 0, stream>>>(attnw16, aimg16);
      attn_src = aimg16;
      win_i++;
    } else {
      gemm_bt<OP_QKV><<<dim3(18, 16), 256, 0, stream>>>(
          hb16, wq, qkv_b + i * 3 * E, nullptr, nullptr, qkv16, ROWS, 3 * E, E);
      attn_mfma<<<dim3(16, Bsz * NH), 256, 0, stream>>>(
          qkv16, attnw16, rel_h_g + (size_t)glob_i * (2 * G - 1) * HD,
          rel_w_g + (size_t)glob_i * (2 * G - 1) * HD, G, G);
      attn_src = attnw16;
      glob_i++;
    }

    gemm_bt<OP_ADD><<<dim3(6, 16), 256, 0, stream>>>(
        attn_src, wp, proj_b + i * E, xbuf, nullptr, xbuf, ROWS, E, E);

    ln_kernel<<<ROWS / 4, 256, 0, stream>>>(xbuf, ln2_w + i * E, ln2_b + i * E, hb16);
    gemm_bt<OP_GELU><<<dim3(24, 16), 256, 0, stream>>>(
        hb16, w1, fc1_b + i * 4 * E, nullptr, nullptr, h1b16, ROWS, 4 * E, E);
    gemm_bt<OP_ADD><<<dim3(6, 16), 256, 0, stream>>>(
        h1b16, w2, fc2_b + i * E, xbuf, nullptr, xbuf, ROWS, E, 4 * E);
  }

  // ---- head ----
  cast_bf16<<<192, 256, 0, stream>>>(out_w, headW16, 256 * 768);
  cast_bf16<<<1536, 256, 0, stream>>>(xbuf, hb16, ROWS * E);
  gemm_bt<OP_HEAD><<<dim3(2, 16), 256, 0, stream>>>(
      hb16, headW16, out_b, nullptr, nullptr, outp, ROWS, 256, E);
}

// Round 5
// 2404.181 us; speedup vs baseline: 6.5326x; 1.0640x over previous
//
#include <hip/hip_runtime.h>
#include <hip/hip_bf16.h>
#include <math.h>

// ---------------- constants ----------------
static constexpr int E   = 768;
static constexpr int NH  = 12;
static constexpr int HD  = 64;
static constexpr int Bsz = 2;
static constexpr int G   = 32;
static constexpr int NTOK = G * G;      // 1024
static constexpr int ROWS = Bsz * NTOK; // 2048
static constexpr int WS  = 14;
static constexpr int NWIN_SIDE = 3;
static constexpr int NWIN = NWIN_SIDE * NWIN_SIDE;
static constexpr int BW  = Bsz * NWIN;   // 18
static constexpr int NW  = WS * WS;      // 196
static constexpr int WROWS = BW * NW;    // 3528
static constexpr int WIN_MASK = 0x6DB;

typedef __attribute__((ext_vector_type(8))) short short8;
typedef __attribute__((ext_vector_type(4))) float f32x4;
typedef unsigned short ushort_t;

__device__ __forceinline__ unsigned short f2bf(float x) {
  union { float f; unsigned u; } v; v.f = x;
  unsigned r = v.u + 0x7fffu + ((v.u >> 16) & 1u);
  return (unsigned short)(r >> 16);
}
__device__ __forceinline__ float bf2f(unsigned short h) {
  union { unsigned u; float f; } v; v.u = ((unsigned)h) << 16;
  return v.f;
}

__device__ __forceinline__ void glds16(const void* g, void* l) {
  __builtin_amdgcn_global_load_lds(
      (const __attribute__((address_space(1))) unsigned*)g,
      (__attribute__((address_space(3))) unsigned*)l, 16, 0, 0);
}

// ---------------- LayerNorm fp32 -> bf16, one wave per row ----------------
__global__ __launch_bounds__(256) void ln_kernel(
    const float* __restrict__ in, const float* __restrict__ w,
    const float* __restrict__ b, ushort_t* __restrict__ out) {
  const int wave = threadIdx.x >> 6, lane = threadIdx.x & 63;
  const int row = blockIdx.x * 4 + wave;
  const float4* r4 = (const float4*)(in + (size_t)row * E);
  float4 v[3];
  v[0] = r4[lane]; v[1] = r4[lane + 64]; v[2] = r4[lane + 128];
  float s = 0.f, s2 = 0.f;
#pragma unroll
  for (int i = 0; i < 3; i++) {
    s += v[i].x + v[i].y + v[i].z + v[i].w;
    s2 += v[i].x * v[i].x + v[i].y * v[i].y + v[i].z * v[i].z + v[i].w * v[i].w;
  }
#pragma unroll
  for (int off = 1; off <= 32; off <<= 1) {
    s += __shfl_xor(s, off);
    s2 += __shfl_xor(s2, off);
  }
  const float mean = s * (1.f / E);
  const float var  = s2 * (1.f / E) - mean * mean;
  const float rs   = rsqrtf(var + 1e-6f);
  ushort_t* o = out + (size_t)row * E;
#pragma unroll
  for (int i = 0; i < 3; i++) {
    const int e0 = (lane + i * 64) * 4;
    ushort4 p;
    p.x = f2bf((v[i].x - mean) * rs * w[e0]     + b[e0]);
    p.y = f2bf((v[i].y - mean) * rs * w[e0 + 1] + b[e0 + 1]);
    p.z = f2bf((v[i].z - mean) * rs * w[e0 + 2] + b[e0 + 2]);
    p.w = f2bf((v[i].w - mean) * rs * w[e0 + 3] + b[e0 + 3]);
    *(ushort4*)&o[e0] = p;
  }
}

// ---------------- bf16 GEMM, A(M,K) x Bt(N,K)^T, global_load_lds staged ----------
// MAP: 0 = direct, 1 = A rows are window rows read from image layout (win_part
// fused; pad rows -> zbuf), 2 = A rows are token rows read from window layout.
enum { OP_QKV = 0, OP_GELU = 1, OP_ADD = 2, OP_POS = 3, OP_HEAD = 4 };

template <int OP, int MAP>
__global__ __launch_bounds__(256) void gemm_bt(
    const ushort_t* __restrict__ A, const ushort_t* __restrict__ Bt,
    const float* __restrict__ bias, const float* __restrict__ res,
    const float* __restrict__ pos, const ushort_t* __restrict__ zbuf,
    void* __restrict__ Cp, int M, int N, int K) {
  __shared__ ushort_t As[128 * 64];
  __shared__ ushort_t Bs[128 * 64];
  const int tid = threadIdx.x, wave = tid >> 6, lane = tid & 63;
  const int lx = lane & 15, ly = lane >> 4;
  const int row0 = blockIdx.y * 128, col0 = blockIdx.x * 128;
  const int wm = (wave >> 1) * 64, wn = (wave & 1) * 64;
  const int rin = lane >> 3, pseg = lane & 7;
  const int lseg = pseg ^ rin;
  f32x4 acc[4][4] = {};

  const ushort_t* aptr[4];
  const ushort_t* bptr[4];
#pragma unroll
  for (int j = 0; j < 4; j++) {
    const int instr = wave * 4 + j;
    int ar = row0 + instr * 8 + rin;
    if (ar >= M) ar = M - 1;
    if (MAP == 1) {
      const int win = ar / NW, t = ar - win * NW;
      const int wy = t / WS, wx = t - wy * WS;
      const int bI = win / NWIN, wr = win - bI * NWIN;
      const int by = wr / NWIN_SIDE, bx = wr - by * NWIN_SIDE;
      const int y = by * WS + wy, x = bx * WS + wx;
      aptr[j] = (y < G && x < G)
                    ? &A[(((size_t)bI * G + y) * G + x) * E + lseg * 8]
                    : &zbuf[lseg * 8];
    } else if (MAP == 2) {
      const int bI = ar >> 10, t = ar & 1023, y = t >> 5, x = t & 31;
      const int by = y / WS, wy = y - by * WS;
      const int bx = x / WS, wx = x - bx * WS;
      const int win = bI * NWIN + by * NWIN_SIDE + bx;
      aptr[j] = &A[((size_t)win * NW + wy * WS + wx) * E + lseg * 8];
    } else {
      aptr[j] = &A[(size_t)ar * K + lseg * 8];
    }
    const int br = col0 + instr * 8 + rin;
    bptr[j] = &Bt[(size_t)br * K + lseg * 8];
  }

  for (int k0 = 0; k0 < K; k0 += 64) {
    __syncthreads();
#pragma unroll
    for (int j = 0; j < 4; j++) {
      const int instr = wave * 4 + j;
      glds16(aptr[j] + k0, &As[instr * 512]);
      glds16(bptr[j] + k0, &Bs[instr * 512]);
    }
    __syncthreads();
#pragma unroll
    for (int kb = 0; kb < 2; kb++) {
      short8 af[4], bfm[4];
#pragma unroll
      for (int m = 0; m < 4; m++) {
        const int r = wm + m * 16 + lx;
        af[m] = *(const short8*)&As[r * 64 + (((kb * 4 + ly) ^ (r & 7)) * 8)];
      }
#pragma unroll
      for (int n = 0; n < 4; n++) {
        const int r = wn + n * 16 + lx;
        bfm[n] = *(const short8*)&Bs[r * 64 + (((kb * 4 + ly) ^ (r & 7)) * 8)];
      }
      __builtin_amdgcn_s_setprio(1);
#pragma unroll
      for (int m = 0; m < 4; m++)
#pragma unroll
        for (int n = 0; n < 4; n++)
          acc[m][n] = __builtin_amdgcn_mfma_f32_16x16x32_bf16(af[m], bfm[n], acc[m][n], 0, 0, 0);
      __builtin_amdgcn_s_setprio(0);
    }
  }

#pragma unroll
  for (int m = 0; m < 4; m++) {
#pragma unroll
    for (int r4 = 0; r4 < 4; r4++) {
      const int gr = row0 + wm + m * 16 + ly * 4 + r4;
      if (gr >= M) continue;
#pragma unroll
      for (int n = 0; n < 4; n++) {
        const int gc = col0 + wn + n * 16 + lx;
        float v = acc[m][n][r4] + bias[gc];
        if (OP == OP_GELU) v = 0.5f * v * (1.f + erff(v * 0.70710678118654752f));
        if (OP == OP_ADD)  v += res[(size_t)gr * N + gc];
        if (OP == OP_POS)  v += pos[(size_t)(gr & 1023) * N + gc];
        if (OP == OP_QKV || OP == OP_GELU)
          ((ushort_t*)Cp)[(size_t)gr * N + gc] = f2bf(v);
        else if (OP == OP_HEAD)
          ((float*)Cp)[(((size_t)(gr >> 10) * 256 + gc) << 10) | (gr & 1023)] = v;
        else
          ((float*)Cp)[(size_t)gr * N + gc] = v;
      }
    }
  }
}

// ---------------- MFMA flash attention, 2 waves x 32 queries ----------------
__global__ __launch_bounds__(128) void attn_mfma(
    const ushort_t* __restrict__ qkv, ushort_t* __restrict__ out,
    const float* __restrict__ relh, const float* __restrict__ relw,
    int Hd, int Wd) {
  const int Ntok = Hd * Wd;
  __shared__ ushort_t smem[11392];
  ushort_t* Ks   = smem;          // main [0,2048): 32x64 swizzled
  ushort_t* Vst  = smem + 2048;   // main [2048,4608): [64 d][40], key XOR-swz
  ushort_t* Ps   = smem + 4608;   // main [4608,5888): [2][16][40]
  ushort_t* Qs   = smem;          // prologue [0,2048): 32x64 swizzled
  ushort_t* RelS = smem + 2048;   // prologue [2048,6144): 64x64 swizzled
  ushort_t* Th   = smem + 6144;   // [32][66]
  ushort_t* Tw   = smem + 8256;   // [32][66]
  ushort_t* khw  = smem + 10368;  // [1024]

  const int tid = threadIdx.x, wave = tid >> 6, lane = tid & 63;
  const int lx = lane & 15, ly = lane >> 4;
  const int bh = blockIdx.y, b = bh / NH, nh = bh % NH;
  const int q0 = blockIdx.x * 32;
  const size_t base = (size_t)b * Ntok * 2304 + nh * 64;

  // ---- stage Q (32x64) swizzled + khw table ----
#pragma unroll
  for (int i = 0; i < 2; i++) {
    const int fv = i * 128 + tid;
    const int row = fv >> 3, dv8 = (fv & 7) * 8;
    const int q = q0 + row;
    short8 v = {};
    if (q < Ntok) v = *(const short8*)&qkv[base + (size_t)q * 2304 + dv8];
    *(short8*)&Qs[(row * 64 + dv8) ^ ((row & 7) << 3)] = v;
  }
  for (int k = tid; k < 1024; k += 128) {
    const int kc = min(k, Ntok - 1);
    const int kh = kc / Wd;
    khw[k] = (ushort_t)((kh << 8) | (kc - kh * Wd));
  }
  __syncthreads();

  // ---- Q fragments ----
  short8 qa[2];
  {
    const int row = wave * 16 + lx;
#pragma unroll
    for (int kb = 0; kb < 2; kb++)
      qa[kb] = *(const short8*)&Qs[(row * 64 + kb * 32 + ly * 8) ^ ((row & 7) << 3)];
  }
  int qh_r[4], qw_r[4];
#pragma unroll
  for (int r = 0; r < 4; r++) {
    const int q = q0 + wave * 16 + ly * 4 + r;
    const int qc = min(q, Ntok - 1);
    qh_r[r] = qc / Wd;
    qw_r[r] = qc - qh_r[r] * Wd;
  }

  // ---- T tables via MFMA: T[q][j] = dot(Q[q], rel[j]) ----
  for (int t = 0; t < 2; t++) {
    const float* rel = t ? relw : relh;
    const int TR = t ? (2 * Wd - 1) : (2 * Hd - 1);
    __syncthreads();
#pragma unroll
    for (int i = 0; i < 4; i++) {
      const int fv = i * 128 + tid;
      const int row = fv >> 3, c8 = (fv & 7) * 8;
      short8 v = {};
      if (row < TR) {
        const float* rp = &rel[(size_t)row * 64 + c8];
        const float4 a = *(const float4*)rp;
        const float4 bq = *(const float4*)(rp + 4);
        v[0] = (short)f2bf(a.x);  v[1] = (short)f2bf(a.y);
        v[2] = (short)f2bf(a.z);  v[3] = (short)f2bf(a.w);
        v[4] = (short)f2bf(bq.x); v[5] = (short)f2bf(bq.y);
        v[6] = (short)f2bf(bq.z); v[7] = (short)f2bf(bq.w);
      }
      *(short8*)&RelS[(row * 64 + c8) ^ ((row & 7) << 3)] = v;
    }
    __syncthreads();
    const int NT = (TR + 15) >> 4;
    ushort_t* T = t ? Tw : Th;
    for (int nt = 0; nt < NT; nt++) {
      f32x4 a = {};
      __builtin_amdgcn_s_setprio(1);
#pragma unroll
      for (int kb = 0; kb < 2; kb++) {
        const int rrow = nt * 16 + lx;
        short8 bfv = *(const short8*)&RelS[(rrow * 64 + kb * 32 + ly * 8) ^ ((rrow & 7) << 3)];
        a = __builtin_amdgcn_mfma_f32_16x16x32_bf16(qa[kb], bfv, a, 0, 0, 0);
      }
      __builtin_amdgcn_s_setprio(0);
#pragma unroll
      for (int reg = 0; reg < 4; reg++)
        T[(wave * 16 + ly * 4 + reg) * 66 + nt * 16 + lx] = f2bf(a[reg]);
    }
  }

  f32x4 o[4] = {};
  float m_[4], l_[4];
#pragma unroll
  for (int r = 0; r < 4; r++) { m_[r] = -3e38f; l_[r] = 0.f; }

  const int nkt = (Ntok + 31) >> 5;
  const int srow = tid >> 3, c7 = tid & 7, dv8s = c7 * 8;
  const int vswz = (c7 & 3) << 3;

  // prefetch tile 0 into registers
  short8 kpre[2], vpre[2];
#pragma unroll
  for (int i = 0; i < 2; i++) {
    const int gk = srow + i * 16;
    short8 kv = {}, vv = {};
    if (gk < Ntok) {
      kv = *(const short8*)&qkv[base + 768 + (size_t)gk * 2304 + dv8s];
      vv = *(const short8*)&qkv[base + 1536 + (size_t)gk * 2304 + dv8s];
    }
    kpre[i] = kv; vpre[i] = vv;
  }

  for (int kt = 0; kt < nkt; kt++) {
    __syncthreads();
    // write prefetched K/V to LDS
#pragma unroll
    for (int i = 0; i < 2; i++) {
      const int row = srow + i * 16;
      *(short8*)&Ks[(row * 64 + dv8s) ^ ((row & 7) << 3)] = kpre[i];
      const int kcol = row ^ vswz;
#pragma unroll
      for (int j = 0; j < 8; j++)
        Vst[(dv8s + j) * 40 + kcol] = (ushort_t)vpre[i][j];
    }
    // issue prefetch for next tile (latency hidden under compute)
    if (kt + 1 < nkt) {
#pragma unroll
      for (int i = 0; i < 2; i++) {
        const int gk = (kt + 1) * 32 + srow + i * 16;
        short8 kv = {}, vv = {};
        if (gk < Ntok) {
          kv = *(const short8*)&qkv[base + 768 + (size_t)gk * 2304 + dv8s];
          vv = *(const short8*)&qkv[base + 1536 + (size_t)gk * 2304 + dv8s];
        }
        kpre[i] = kv; vpre[i] = vv;
      }
    }
    __syncthreads();

    // ---- QK^T ----
    f32x4 c[2] = {};
    __builtin_amdgcn_s_setprio(1);
#pragma unroll
    for (int kb = 0; kb < 2; kb++)
#pragma unroll
      for (int ct = 0; ct < 2; ct++) {
        const int krow = ct * 16 + lx;
        short8 kf = *(const short8*)&Ks[(krow * 64 + kb * 32 + ly * 8) ^ ((krow & 7) << 3)];
        c[ct] = __builtin_amdgcn_mfma_f32_16x16x32_bf16(qa[kb], kf, c[ct], 0, 0, 0);
      }
    __builtin_amdgcn_s_setprio(0);

    // ---- scores + bias ----
    const int k0a = kt * 32 + lx, k1a = k0a + 16;
    const int tv0 = khw[k0a], tv1 = khw[k1a];
    const int kh0 = tv0 >> 8, kw0 = tv0 & 255;
    const int kh1 = tv1 >> 8, kw1 = tv1 & 255;
    float pv0[4], pv1[4], mt[4];
#pragma unroll
    for (int r = 0; r < 4; r++) {
      const int trow = (wave * 16 + ly * 4 + r) * 66;
      float s0 = c[0][r] * 0.125f + bf2f(Th[trow + qh_r[r] - kh0 + Hd - 1])
               + bf2f(Tw[trow + qw_r[r] - kw0 + Wd - 1]);
      float s1 = c[1][r] * 0.125f + bf2f(Th[trow + qh_r[r] - kh1 + Hd - 1])
               + bf2f(Tw[trow + qw_r[r] - kw1 + Wd - 1]);
      if (k0a >= Ntok) s0 = -1e30f;
      if (k1a >= Ntok) s1 = -1e30f;
      pv0[r] = s0; pv1[r] = s1;
      mt[r] = fmaxf(s0, s1);
    }
    // ---- defer-max (T13): rescale only when max grows past threshold ----
    const float dmax = fmaxf(fmaxf(mt[0] - m_[0], mt[1] - m_[1]),
                             fmaxf(mt[2] - m_[2], mt[3] - m_[3]));
    if (!__all(dmax <= 8.f)) {
#pragma unroll
      for (int r = 0; r < 4; r++) {
        float mr = mt[r];
#pragma unroll
        for (int off = 1; off <= 8; off <<= 1) mr = fmaxf(mr, __shfl_xor(mr, off));
        const float mn = fmaxf(m_[r], mr);
        const float sc = __expf(m_[r] - mn);
        m_[r] = mn; l_[r] *= sc;
#pragma unroll
        for (int dt = 0; dt < 4; dt++) o[dt][r] *= sc;
      }
    }
#pragma unroll
    for (int r = 0; r < 4; r++) {
      const float p0 = __expf(pv0[r] - m_[r]);
      const float p1 = __expf(pv1[r] - m_[r]);
      l_[r] += p0 + p1;  // per-lane partial; reduced once at the end
      const int pb = wave * 640 + (ly * 4 + r) * 40;
      Ps[pb + lx]      = f2bf(p0);
      Ps[pb + 16 + lx] = f2bf(p1);
    }
    // ---- PV ----
    short8 pf = *(const short8*)&Ps[wave * 640 + lx * 40 + ly * 8];
    __builtin_amdgcn_s_setprio(1);
#pragma unroll
    for (int dt = 0; dt < 4; dt++) {
      const int drow = dt * 16 + lx;
      short8 vf = *(const short8*)&Vst[drow * 40 + ((ly * 8) ^ (((drow >> 3) & 3) << 3))];
      o[dt] = __builtin_amdgcn_mfma_f32_16x16x32_bf16(pf, vf, o[dt], 0, 0, 0);
    }
    __builtin_amdgcn_s_setprio(0);
  }

  // ---- epilogue: single l-reduction + store ----
#pragma unroll
  for (int r = 0; r < 4; r++) {
#pragma unroll
    for (int off = 1; off <= 8; off <<= 1) l_[r] += __shfl_xor(l_[r], off);
    const int q = q0 + wave * 16 + ly * 4 + r;
    if (q >= Ntok) continue;
    const float inv = 1.f / l_[r];
#pragma unroll
    for (int dt = 0; dt < 4; dt++)
      out[((size_t)b * Ntok + q) * E + nh * 64 + dt * 16 + lx] = f2bf(o[dt][r] * inv);
  }
}

// ---------------- im2col ----------------
__global__ __launch_bounds__(256) void im2col(const float* __restrict__ x,
                                              ushort_t* __restrict__ out) {
  const int blk = blockIdx.x;
  const int b = blk >> 10, t = blk & 1023, gy = t >> 5, gx = t & 31;
  for (int k = threadIdx.x; k < 768; k += 256) {
    const int ci = k >> 8, rem = k & 255, py = rem >> 4, px = rem & 15;
    out[(size_t)blk * 768 + k] =
        f2bf(x[(((size_t)b * 3 + ci) * 512 + gy * 16 + py) * 512 + gx * 16 + px]);
  }
}

// ---------------- per-layer weight transpose fp32(K,N) -> bf16(N,K) ----------------
__global__ __launch_bounds__(256) void prep_wt(
    const float* __restrict__ qkvw, const float* __restrict__ projw,
    const float* __restrict__ fc1w, const float* __restrict__ fc2w,
    ushort_t* __restrict__ wq, ushort_t* __restrict__ wp,
    ushort_t* __restrict__ w1, ushort_t* __restrict__ w2) {
  __shared__ float tile[32][33];
  const int blk = blockIdx.x;
  const float* W; ushort_t* Wt; int Kd, Nd, tn, tk;
  if (blk < 1728)      { W = qkvw;  Wt = wq; Kd = 768;  Nd = 2304; tn = blk % 72;          tk = blk / 72; }
  else if (blk < 2304) { W = projw; Wt = wp; Kd = 768;  Nd = 768;  tn = (blk - 1728) % 24; tk = (blk - 1728) / 24; }
  else if (blk < 4608) { W = fc1w;  Wt = w1; Kd = 768;  Nd = 3072; tn = (blk - 2304) % 96; tk = (blk - 2304) / 96; }
  else                 { W = fc2w;  Wt = w2; Kd = 3072; Nd = 768;  tn = (blk - 4608) % 24; tk = (blk - 4608) / 24; }
  const int k0 = tk * 32, n0 = tn * 32;
  const int c = threadIdx.x & 31, r8 = threadIdx.x >> 5;
#pragma unroll
  for (int i = 0; i < 4; i++) {
    const int kr = i * 8 + r8;
    tile[kr][c] = W[(size_t)(k0 + kr) * Nd + n0 + c];
  }
  __syncthreads();
#pragma unroll
  for (int i = 0; i < 4; i++) {
    const int nr = i * 8 + r8;
    Wt[(size_t)(n0 + nr) * Kd + k0 + c] = f2bf(tile[c][nr]);
  }
}

// ---------------- elementwise fp32 -> bf16 ----------------
__global__ __launch_bounds__(256) void cast_bf16(const float* __restrict__ in,
                                                 ushort_t* __restrict__ out, int n) {
  const int idx = (blockIdx.x * 256 + threadIdx.x) * 4;
  if (idx + 3 < n) {
    const float4 v = *(const float4*)&in[idx];
    ushort4 p;
    p.x = f2bf(v.x); p.y = f2bf(v.y); p.z = f2bf(v.z); p.w = f2bf(v.w);
    *(ushort4*)&out[idx] = p;
  }
}

__global__ __launch_bounds__(256) void zinit(ushort_t* __restrict__ z) {
  z[blockIdx.x * 256 + threadIdx.x] = 0;
}

// ---------------- launch ----------------
extern "C" void kernel_launch(void* const* d_in, const int* in_sizes, int n_in,
                              void* d_out, int out_size, void* d_ws, size_t ws_size,
                              hipStream_t stream) {
  const float* x_in     = (const float*)d_in[0];
  const float* patch_w  = (const float*)d_in[1];
  const float* patch_b  = (const float*)d_in[2];
  const float* pos_emb  = (const float*)d_in[3];
  const float* ln1_w    = (const float*)d_in[4];
  const float* ln1_b    = (const float*)d_in[5];
  const float* qkv_w    = (const float*)d_in[6];
  const float* qkv_b    = (const float*)d_in[7];
  const float* proj_w   = (const float*)d_in[8];
  const float* proj_b   = (const float*)d_in[9];
  const float* rel_h_w  = (const float*)d_in[10];
  const float* rel_w_w  = (const float*)d_in[11];
  const float* rel_h_g  = (const float*)d_in[12];
  const float* rel_w_g  = (const float*)d_in[13];
  const float* ln2_w    = (const float*)d_in[14];
  const float* ln2_b    = (const float*)d_in[15];
  const float* fc1_w    = (const float*)d_in[16];
  const float* fc1_b    = (const float*)d_in[17];
  const float* fc2_w    = (const float*)d_in[18];
  const float* fc2_b    = (const float*)d_in[19];
  const float* out_w    = (const float*)d_in[20];
  const float* out_b    = (const float*)d_in[21];
  float* outp = (float*)d_out;

  float* xbuf = (float*)d_ws;                                   // 2048*768 f32
  ushort_t* hb16    = (ushort_t*)(xbuf + (size_t)ROWS * E);     // 2048*768
  ushort_t* qkv16   = hb16 + (size_t)ROWS * E;                  // 3528*2304
  ushort_t* attnw16 = qkv16 + (size_t)WROWS * 3 * E;            // 3528*768
  ushort_t* wtbuf   = attnw16 + (size_t)WROWS * E;              // 9216*768
  ushort_t* wq = wtbuf;                 // 2304*768
  ushort_t* wp = wq + 2304 * 768;       // 768*768
  ushort_t* w1 = wp + 768 * 768;        // 3072*768
  ushort_t* w2 = w1 + 3072 * 768;       // 768*3072
  ushort_t* zbuf = wtbuf + (size_t)9216 * 768;  // 1024 zeros
  ushort_t* imb16 = hb16;
  ushort_t* h1b16 = qkv16;
  ushort_t* pwT16 = wtbuf;
  ushort_t* headW16 = wtbuf;

  zinit<<<4, 256, 0, stream>>>(zbuf);

  // ---- patch embed as GEMM ----
  cast_bf16<<<576, 256, 0, stream>>>(patch_w, pwT16, 768 * 768);
  im2col<<<ROWS, 256, 0, stream>>>(x_in, imb16);
  gemm_bt<OP_POS, 0><<<dim3(6, 16), 256, 0, stream>>>(
      imb16, pwT16, patch_b, nullptr, pos_emb, nullptr, xbuf, ROWS, E, E);

  int win_i = 0, glob_i = 0;
  for (int i = 0; i < 12; i++) {
    const bool is_win = (WIN_MASK >> i) & 1;

    prep_wt<<<6912, 256, 0, stream>>>(
        qkv_w + (size_t)i * E * 3 * E, proj_w + (size_t)i * E * E,
        fc1_w + (size_t)i * E * 4 * E, fc2_w + (size_t)i * 4 * E * E,
        wq, wp, w1, w2);

    ln_kernel<<<ROWS / 4, 256, 0, stream>>>(xbuf, ln1_w + i * E, ln1_b + i * E, hb16);

    const ushort_t* attn_src;
    if (is_win) {
      gemm_bt<OP_QKV, 1><<<dim3(18, 28), 256, 0, stream>>>(
          hb16, wq, qkv_b + i * 3 * E, nullptr, nullptr, zbuf, qkv16, WROWS, 3 * E, E);
      attn_mfma<<<dim3(7, BW * NH), 128, 0, stream>>>(
          qkv16, attnw16, rel_h_w + (size_t)win_i * (2 * WS - 1) * HD,
          rel_w_w + (size_t)win_i * (2 * WS - 1) * HD, WS, WS);
      win_i++;
      attn_src = attnw16;
    } else {
      gemm_bt<OP_QKV, 0><<<dim3(18, 16), 256, 0, stream>>>(
          hb16, wq, qkv_b + i * 3 * E, nullptr, nullptr, nullptr, qkv16, ROWS, 3 * E, E);
      attn_mfma<<<dim3(32, Bsz * NH), 128, 0, stream>>>(
          qkv16, attnw16, rel_h_g + (size_t)glob_i * (2 * G - 1) * HD,
          rel_w_g + (size_t)glob_i * (2 * G - 1) * HD, G, G);
      glob_i++;
      attn_src = attnw16;
    }

    if (is_win)
      gemm_bt<OP_ADD, 2><<<dim3(6, 16), 256, 0, stream>>>(
          attn_src, wp, proj_b + i * E, xbuf, nullptr, nullptr, xbuf, ROWS, E, E);
    else
      gemm_bt<OP_ADD, 0><<<dim3(6, 16), 256, 0, stream>>>(
          attn_src, wp, proj_b + i * E, xbuf, nullptr, nullptr, xbuf, ROWS, E, E);

    ln_kernel<<<ROWS / 4, 256, 0, stream>>>(xbuf, ln2_w + i * E, ln2_b + i * E, hb16);
    gemm_bt<OP_GELU, 0><<<dim3(24, 16), 256, 0, stream>>>(
        hb16, w1, fc1_b + i * 4 * E, nullptr, nullptr, nullptr, h1b16, ROWS, 4 * E, E);
    gemm_bt<OP_ADD, 0><<<dim3(6, 16), 256, 0, stream>>>(
        h1b16, w2, fc2_b + i * E, xbuf, nullptr, nullptr, xbuf, ROWS, E, 4 * E);
  }

  // ---- head ----
  cast_bf16<<<192, 256, 0, stream>>>(out_w, headW16, 256 * 768);
  cast_bf16<<<1536, 256, 0, stream>>>(xbuf, hb16, ROWS * E);
  gemm_bt<OP_HEAD, 0><<<dim3(2, 16), 256, 0, stream>>>(
      hb16, headW16, out_b, nullptr, nullptr, nullptr, outp, ROWS, 256, E);
}

// Round 6
// 1834.308 us; speedup vs baseline: 8.5621x; 1.3107x over previous
//
#include <hip/hip_runtime.h>
#include <hip/hip_bf16.h>
#include <math.h>

// ---------------- constants ----------------
static constexpr int E   = 768;
static constexpr int NH  = 12;
static constexpr int HD  = 64;
static constexpr int Bsz = 2;
static constexpr int G   = 32;
static constexpr int NTOK = G * G;      // 1024
static constexpr int ROWS = Bsz * NTOK; // 2048
static constexpr int WS  = 14;
static constexpr int NWIN_SIDE = 3;
static constexpr int NWIN = NWIN_SIDE * NWIN_SIDE;
static constexpr int BW  = Bsz * NWIN;   // 18
static constexpr int NW  = WS * WS;      // 196
static constexpr int WROWS = BW * NW;    // 3528
static constexpr int WIN_MASK = 0x6DB;

typedef __attribute__((ext_vector_type(8))) short short8;
typedef __attribute__((ext_vector_type(4))) float f32x4;
typedef unsigned short ushort_t;

__device__ __forceinline__ unsigned short f2bf(float x) {
  union { float f; unsigned u; } v; v.f = x;
  unsigned r = v.u + 0x7fffu + ((v.u >> 16) & 1u);
  return (unsigned short)(r >> 16);
}
__device__ __forceinline__ float bf2f(unsigned short h) {
  union { unsigned u; float f; } v; v.u = ((unsigned)h) << 16;
  return v.f;
}

__device__ __forceinline__ void glds16(const void* g, void* l) {
  __builtin_amdgcn_global_load_lds(
      (const __attribute__((address_space(1))) unsigned*)g,
      (__attribute__((address_space(3))) unsigned*)l, 16, 0, 0);
}

// ---------------- LayerNorm fp32 -> bf16, one wave per row ----------------
__global__ __launch_bounds__(256) void ln_kernel(
    const float* __restrict__ in, const float* __restrict__ w,
    const float* __restrict__ b, ushort_t* __restrict__ out) {
  const int wave = threadIdx.x >> 6, lane = threadIdx.x & 63;
  const int row = blockIdx.x * 4 + wave;
  const float4* r4 = (const float4*)(in + (size_t)row * E);
  float4 v[3];
  v[0] = r4[lane]; v[1] = r4[lane + 64]; v[2] = r4[lane + 128];
  float s = 0.f, s2 = 0.f;
#pragma unroll
  for (int i = 0; i < 3; i++) {
    s += v[i].x + v[i].y + v[i].z + v[i].w;
    s2 += v[i].x * v[i].x + v[i].y * v[i].y + v[i].z * v[i].z + v[i].w * v[i].w;
  }
#pragma unroll
  for (int off = 1; off <= 32; off <<= 1) {
    s += __shfl_xor(s, off);
    s2 += __shfl_xor(s2, off);
  }
  const float mean = s * (1.f / E);
  const float var  = s2 * (1.f / E) - mean * mean;
  const float rs   = rsqrtf(var + 1e-6f);
  ushort_t* o = out + (size_t)row * E;
#pragma unroll
  for (int i = 0; i < 3; i++) {
    const int e0 = (lane + i * 64) * 4;
    ushort4 p;
    p.x = f2bf((v[i].x - mean) * rs * w[e0]     + b[e0]);
    p.y = f2bf((v[i].y - mean) * rs * w[e0 + 1] + b[e0 + 1]);
    p.z = f2bf((v[i].z - mean) * rs * w[e0 + 2] + b[e0 + 2]);
    p.w = f2bf((v[i].w - mean) * rs * w[e0 + 3] + b[e0 + 3]);
    *(ushort4*)&o[e0] = p;
  }
}

// ---------------- bf16 GEMM, 64x64 tile, dbuf 2-phase, XCD swizzle ----------
// MAP: 0 = direct, 1 = A rows = window rows from image layout (pad -> zbuf),
// 2 = A rows = token rows from window layout.
enum { OP_QKV = 0, OP_GELU = 1, OP_ADD = 2, OP_POS = 3, OP_HEAD = 4 };

template <int OP, int MAP>
__global__ __launch_bounds__(256) void gemm_bt(
    const ushort_t* __restrict__ A, const ushort_t* __restrict__ Bt,
    const float* __restrict__ bias, const float* __restrict__ res,
    const float* __restrict__ pos, const ushort_t* __restrict__ zbuf,
    void* __restrict__ Cp, int M, int N, int K, int ncol) {
  __shared__ ushort_t As[2][64 * 64];
  __shared__ ushort_t Bs[2][64 * 64];
  const int tid = threadIdx.x, wave = tid >> 6, lane = tid & 63;
  const int lx = lane & 15, ly = lane >> 4;

  // bijective XCD-chunked swizzle (m204)
  const int nwg = gridDim.x;
  const int q = nwg >> 3, r = nwg & 7;
  const int xcd = blockIdx.x & 7, loc = blockIdx.x >> 3;
  const int wgid = ((xcd < r) ? xcd * (q + 1) : r * (q + 1) + (xcd - r) * q) + loc;
  const int brow = wgid / ncol, bcol = wgid - brow * ncol;
  const int row0 = brow * 64, col0 = bcol * 64;
  const int wm = (wave >> 1) * 32, wn = (wave & 1) * 32;
  const int rin = lane >> 3, pseg = lane & 7;
  const int lseg = pseg ^ rin;
  f32x4 acc[2][2] = {};

  const ushort_t* aptr[2];
  const ushort_t* bptr[2];
#pragma unroll
  for (int j = 0; j < 2; j++) {
    const int slot = wave * 2 + j;
    int ar = row0 + slot * 8 + rin;
    if (ar >= M) ar = M - 1;
    if (MAP == 1) {
      const int win = ar / NW, t = ar - win * NW;
      const int wy = t / WS, wx = t - wy * WS;
      const int bI = win / NWIN, wr = win - bI * NWIN;
      const int by = wr / NWIN_SIDE, bx = wr - by * NWIN_SIDE;
      const int y = by * WS + wy, x = bx * WS + wx;
      aptr[j] = (y < G && x < G)
                    ? &A[(((size_t)bI * G + y) * G + x) * E + lseg * 8]
                    : &zbuf[lseg * 8];
    } else if (MAP == 2) {
      const int bI = ar >> 10, t = ar & 1023, y = t >> 5, x = t & 31;
      const int by = y / WS, wy = y - by * WS;
      const int bx = x / WS, wx = x - bx * WS;
      const int win = bI * NWIN + by * NWIN_SIDE + bx;
      aptr[j] = &A[((size_t)win * NW + wy * WS + wx) * E + lseg * 8];
    } else {
      aptr[j] = &A[(size_t)ar * K + lseg * 8];
    }
    const int br = col0 + slot * 8 + rin;  // N is a multiple of 64
    bptr[j] = &Bt[(size_t)br * K + lseg * 8];
  }

  // prologue: stage tile 0
#pragma unroll
  for (int j = 0; j < 2; j++) {
    const int slot = wave * 2 + j;
    glds16(aptr[j], &As[0][slot * 512]);
    glds16(bptr[j], &Bs[0][slot * 512]);
  }
  __syncthreads();

  const int nt = K >> 6;
  int cur = 0;
  for (int t = 0; t < nt; t++) {
    if (t + 1 < nt) {
      const int k1 = (t + 1) << 6;
#pragma unroll
      for (int j = 0; j < 2; j++) {
        const int slot = wave * 2 + j;
        glds16(aptr[j] + k1, &As[cur ^ 1][slot * 512]);
        glds16(bptr[j] + k1, &Bs[cur ^ 1][slot * 512]);
      }
    }
#pragma unroll
    for (int kb = 0; kb < 2; kb++) {
      short8 af[2], bfm[2];
#pragma unroll
      for (int m = 0; m < 2; m++) {
        const int rr = wm + m * 16 + lx;
        af[m] = *(const short8*)&As[cur][rr * 64 + (((kb * 4 + ly) ^ (rr & 7)) * 8)];
      }
#pragma unroll
      for (int n = 0; n < 2; n++) {
        const int rr = wn + n * 16 + lx;
        bfm[n] = *(const short8*)&Bs[cur][rr * 64 + (((kb * 4 + ly) ^ (rr & 7)) * 8)];
      }
      __builtin_amdgcn_s_setprio(1);
#pragma unroll
      for (int m = 0; m < 2; m++)
#pragma unroll
        for (int n = 0; n < 2; n++)
          acc[m][n] = __builtin_amdgcn_mfma_f32_16x16x32_bf16(af[m], bfm[n], acc[m][n], 0, 0, 0);
      __builtin_amdgcn_s_setprio(0);
    }
    __syncthreads();
    cur ^= 1;
  }

#pragma unroll
  for (int m = 0; m < 2; m++) {
#pragma unroll
    for (int r4 = 0; r4 < 4; r4++) {
      const int gr = row0 + wm + m * 16 + ly * 4 + r4;
      if (gr >= M) continue;
#pragma unroll
      for (int n = 0; n < 2; n++) {
        const int gc = col0 + wn + n * 16 + lx;
        float v = acc[m][n][r4] + bias[gc];
        if (OP == OP_GELU) v = 0.5f * v * (1.f + erff(v * 0.70710678118654752f));
        if (OP == OP_ADD)  v += res[(size_t)gr * N + gc];
        if (OP == OP_POS)  v += pos[(size_t)(gr & 1023) * N + gc];
        if (OP == OP_QKV || OP == OP_GELU)
          ((ushort_t*)Cp)[(size_t)gr * N + gc] = f2bf(v);
        else if (OP == OP_HEAD)
          ((float*)Cp)[(((size_t)(gr >> 10) * 256 + gc) << 10) | (gr & 1023)] = v;
        else
          ((float*)Cp)[(size_t)gr * N + gc] = v;
      }
    }
  }
}

// ---------------- MFMA flash attention, 2 waves x 32 queries ----------------
__global__ __launch_bounds__(128) void attn_mfma(
    const ushort_t* __restrict__ qkv, ushort_t* __restrict__ out,
    const float* __restrict__ relh, const float* __restrict__ relw,
    int Hd, int Wd) {
  const int Ntok = Hd * Wd;
  __shared__ ushort_t smem[11392];
  ushort_t* Ks   = smem;          // main [0,2048): 32x64 swizzled
  ushort_t* Vst  = smem + 2048;   // main: [64 d][40], key XOR-swz
  ushort_t* Ps   = smem + 4608;   // main: [2][16][40]
  ushort_t* Qs   = smem;          // prologue: 32x64 swizzled
  ushort_t* RelS = smem + 2048;   // prologue: 64x64 swizzled
  ushort_t* Th   = smem + 6144;   // [32][66]
  ushort_t* Tw   = smem + 8256;   // [32][66]
  ushort_t* khw  = smem + 10368;  // [1024]

  const int tid = threadIdx.x, wave = tid >> 6, lane = tid & 63;
  const int lx = lane & 15, ly = lane >> 4;
  const int bh = blockIdx.y, b = bh / NH, nh = bh % NH;
  const int q0 = blockIdx.x * 32;
  const size_t base = (size_t)b * Ntok * 2304 + nh * 64;

#pragma unroll
  for (int i = 0; i < 2; i++) {
    const int fv = i * 128 + tid;
    const int row = fv >> 3, dv8 = (fv & 7) * 8;
    const int qq = q0 + row;
    short8 v = {};
    if (qq < Ntok) v = *(const short8*)&qkv[base + (size_t)qq * 2304 + dv8];
    *(short8*)&Qs[(row * 64 + dv8) ^ ((row & 7) << 3)] = v;
  }
  for (int k = tid; k < 1024; k += 128) {
    const int kc = min(k, Ntok - 1);
    const int kh = kc / Wd;
    khw[k] = (ushort_t)((kh << 8) | (kc - kh * Wd));
  }
  __syncthreads();

  short8 qa[2];
  {
    const int row = wave * 16 + lx;
#pragma unroll
    for (int kb = 0; kb < 2; kb++)
      qa[kb] = *(const short8*)&Qs[(row * 64 + kb * 32 + ly * 8) ^ ((row & 7) << 3)];
  }
  int qh_r[4], qw_r[4];
#pragma unroll
  for (int r = 0; r < 4; r++) {
    const int qq = q0 + wave * 16 + ly * 4 + r;
    const int qc = min(qq, Ntok - 1);
    qh_r[r] = qc / Wd;
    qw_r[r] = qc - qh_r[r] * Wd;
  }

  for (int t = 0; t < 2; t++) {
    const float* rel = t ? relw : relh;
    const int TR = t ? (2 * Wd - 1) : (2 * Hd - 1);
    __syncthreads();
#pragma unroll
    for (int i = 0; i < 4; i++) {
      const int fv = i * 128 + tid;
      const int row = fv >> 3, c8 = (fv & 7) * 8;
      short8 v = {};
      if (row < TR) {
        const float* rp = &rel[(size_t)row * 64 + c8];
        const float4 a = *(const float4*)rp;
        const float4 bq = *(const float4*)(rp + 4);
        v[0] = (short)f2bf(a.x);  v[1] = (short)f2bf(a.y);
        v[2] = (short)f2bf(a.z);  v[3] = (short)f2bf(a.w);
        v[4] = (short)f2bf(bq.x); v[5] = (short)f2bf(bq.y);
        v[6] = (short)f2bf(bq.z); v[7] = (short)f2bf(bq.w);
      }
      *(short8*)&RelS[(row * 64 + c8) ^ ((row & 7) << 3)] = v;
    }
    __syncthreads();
    const int NT = (TR + 15) >> 4;
    ushort_t* T = t ? Tw : Th;
    for (int nt = 0; nt < NT; nt++) {
      f32x4 a = {};
      __builtin_amdgcn_s_setprio(1);
#pragma unroll
      for (int kb = 0; kb < 2; kb++) {
        const int rrow = nt * 16 + lx;
        short8 bfv = *(const short8*)&RelS[(rrow * 64 + kb * 32 + ly * 8) ^ ((rrow & 7) << 3)];
        a = __builtin_amdgcn_mfma_f32_16x16x32_bf16(qa[kb], bfv, a, 0, 0, 0);
      }
      __builtin_amdgcn_s_setprio(0);
#pragma unroll
      for (int reg = 0; reg < 4; reg++)
        T[(wave * 16 + ly * 4 + reg) * 66 + nt * 16 + lx] = f2bf(a[reg]);
    }
  }

  f32x4 o[4] = {};
  float m_[4], l_[4];
#pragma unroll
  for (int r = 0; r < 4; r++) { m_[r] = -3e38f; l_[r] = 0.f; }

  const int nkt = (Ntok + 31) >> 5;
  const int srow = tid >> 3, c7 = tid & 7, dv8s = c7 * 8;
  const int vswz = (c7 & 3) << 3;

  short8 kpre[2], vpre[2];
#pragma unroll
  for (int i = 0; i < 2; i++) {
    const int gk = srow + i * 16;
    short8 kv = {}, vv = {};
    if (gk < Ntok) {
      kv = *(const short8*)&qkv[base + 768 + (size_t)gk * 2304 + dv8s];
      vv = *(const short8*)&qkv[base + 1536 + (size_t)gk * 2304 + dv8s];
    }
    kpre[i] = kv; vpre[i] = vv;
  }

  for (int kt = 0; kt < nkt; kt++) {
    __syncthreads();
#pragma unroll
    for (int i = 0; i < 2; i++) {
      const int row = srow + i * 16;
      *(short8*)&Ks[(row * 64 + dv8s) ^ ((row & 7) << 3)] = kpre[i];
      const int kcol = row ^ vswz;
#pragma unroll
      for (int j = 0; j < 8; j++)
        Vst[(dv8s + j) * 40 + kcol] = (ushort_t)vpre[i][j];
    }
    if (kt + 1 < nkt) {
#pragma unroll
      for (int i = 0; i < 2; i++) {
        const int gk = (kt + 1) * 32 + srow + i * 16;
        short8 kv = {}, vv = {};
        if (gk < Ntok) {
          kv = *(const short8*)&qkv[base + 768 + (size_t)gk * 2304 + dv8s];
          vv = *(const short8*)&qkv[base + 1536 + (size_t)gk * 2304 + dv8s];
        }
        kpre[i] = kv; vpre[i] = vv;
      }
    }
    __syncthreads();

    f32x4 c[2] = {};
    __builtin_amdgcn_s_setprio(1);
#pragma unroll
    for (int kb = 0; kb < 2; kb++)
#pragma unroll
      for (int ct = 0; ct < 2; ct++) {
        const int krow = ct * 16 + lx;
        short8 kf = *(const short8*)&Ks[(krow * 64 + kb * 32 + ly * 8) ^ ((krow & 7) << 3)];
        c[ct] = __builtin_amdgcn_mfma_f32_16x16x32_bf16(qa[kb], kf, c[ct], 0, 0, 0);
      }
    __builtin_amdgcn_s_setprio(0);

    const int k0a = kt * 32 + lx, k1a = k0a + 16;
    const int tv0 = khw[k0a], tv1 = khw[k1a];
    const int kh0 = tv0 >> 8, kw0 = tv0 & 255;
    const int kh1 = tv1 >> 8, kw1 = tv1 & 255;
    float pv0[4], pv1[4], mt[4];
#pragma unroll
    for (int r = 0; r < 4; r++) {
      const int trow = (wave * 16 + ly * 4 + r) * 66;
      float s0 = c[0][r] * 0.125f + bf2f(Th[trow + qh_r[r] - kh0 + Hd - 1])
               + bf2f(Tw[trow + qw_r[r] - kw0 + Wd - 1]);
      float s1 = c[1][r] * 0.125f + bf2f(Th[trow + qh_r[r] - kh1 + Hd - 1])
               + bf2f(Tw[trow + qw_r[r] - kw1 + Wd - 1]);
      if (k0a >= Ntok) s0 = -1e30f;
      if (k1a >= Ntok) s1 = -1e30f;
      pv0[r] = s0; pv1[r] = s1;
      mt[r] = fmaxf(s0, s1);
    }
    const float dmax = fmaxf(fmaxf(mt[0] - m_[0], mt[1] - m_[1]),
                             fmaxf(mt[2] - m_[2], mt[3] - m_[3]));
    if (!__all(dmax <= 8.f)) {
#pragma unroll
      for (int r = 0; r < 4; r++) {
        float mr = mt[r];
#pragma unroll
        for (int off = 1; off <= 8; off <<= 1) mr = fmaxf(mr, __shfl_xor(mr, off));
        const float mn = fmaxf(m_[r], mr);
        const float sc = __expf(m_[r] - mn);
        m_[r] = mn; l_[r] *= sc;
#pragma unroll
        for (int dt = 0; dt < 4; dt++) o[dt][r] *= sc;
      }
    }
#pragma unroll
    for (int r = 0; r < 4; r++) {
      const float p0 = __expf(pv0[r] - m_[r]);
      const float p1 = __expf(pv1[r] - m_[r]);
      l_[r] += p0 + p1;
      const int pb = wave * 640 + (ly * 4 + r) * 40;
      Ps[pb + lx]      = f2bf(p0);
      Ps[pb + 16 + lx] = f2bf(p1);
    }
    short8 pf = *(const short8*)&Ps[wave * 640 + lx * 40 + ly * 8];
    __builtin_amdgcn_s_setprio(1);
#pragma unroll
    for (int dt = 0; dt < 4; dt++) {
      const int drow = dt * 16 + lx;
      short8 vf = *(const short8*)&Vst[drow * 40 + ((ly * 8) ^ (((drow >> 3) & 3) << 3))];
      o[dt] = __builtin_amdgcn_mfma_f32_16x16x32_bf16(pf, vf, o[dt], 0, 0, 0);
    }
    __builtin_amdgcn_s_setprio(0);
  }

#pragma unroll
  for (int r = 0; r < 4; r++) {
#pragma unroll
    for (int off = 1; off <= 8; off <<= 1) l_[r] += __shfl_xor(l_[r], off);
    const int qq = q0 + wave * 16 + ly * 4 + r;
    if (qq >= Ntok) continue;
    const float inv = 1.f / l_[r];
#pragma unroll
    for (int dt = 0; dt < 4; dt++)
      out[((size_t)b * Ntok + qq) * E + nh * 64 + dt * 16 + lx] = f2bf(o[dt][r] * inv);
  }
}

// ---------------- im2col ----------------
__global__ __launch_bounds__(256) void im2col(const float* __restrict__ x,
                                              ushort_t* __restrict__ out) {
  const int blk = blockIdx.x;
  const int b = blk >> 10, t = blk & 1023, gy = t >> 5, gx = t & 31;
  for (int k = threadIdx.x; k < 768; k += 256) {
    const int ci = k >> 8, rem = k & 255, py = rem >> 4, px = rem & 15;
    out[(size_t)blk * 768 + k] =
        f2bf(x[(((size_t)b * 3 + ci) * 512 + gy * 16 + py) * 512 + gx * 16 + px]);
  }
}

// ---------------- per-layer weight transpose fp32(K,N) -> bf16(N,K) ----------------
__global__ __launch_bounds__(256) void prep_wt(
    const float* __restrict__ qkvw, const float* __restrict__ projw,
    const float* __restrict__ fc1w, const float* __restrict__ fc2w,
    ushort_t* __restrict__ wq, ushort_t* __restrict__ wp,
    ushort_t* __restrict__ w1, ushort_t* __restrict__ w2) {
  __shared__ float tile[32][33];
  const int blk = blockIdx.x;
  const float* W; ushort_t* Wt; int Kd, Nd, tn, tk;
  if (blk < 1728)      { W = qkvw;  Wt = wq; Kd = 768;  Nd = 2304; tn = blk % 72;          tk = blk / 72; }
  else if (blk < 2304) { W = projw; Wt = wp; Kd = 768;  Nd = 768;  tn = (blk - 1728) % 24; tk = (blk - 1728) / 24; }
  else if (blk < 4608) { W = fc1w;  Wt = w1; Kd = 768;  Nd = 3072; tn = (blk - 2304) % 96; tk = (blk - 2304) / 96; }
  else                 { W = fc2w;  Wt = w2; Kd = 3072; Nd = 768;  tn = (blk - 4608) % 24; tk = (blk - 4608) / 24; }
  const int k0 = tk * 32, n0 = tn * 32;
  const int c = threadIdx.x & 31, r8 = threadIdx.x >> 5;
#pragma unroll
  for (int i = 0; i < 4; i++) {
    const int kr = i * 8 + r8;
    tile[kr][c] = W[(size_t)(k0 + kr) * Nd + n0 + c];
  }
  __syncthreads();
#pragma unroll
  for (int i = 0; i < 4; i++) {
    const int nr = i * 8 + r8;
    Wt[(size_t)(n0 + nr) * Kd + k0 + c] = f2bf(tile[c][nr]);
  }
}

// ---------------- elementwise fp32 -> bf16 ----------------
__global__ __launch_bounds__(256) void cast_bf16(const float* __restrict__ in,
                                                 ushort_t* __restrict__ out, int n) {
  const int idx = (blockIdx.x * 256 + threadIdx.x) * 4;
  if (idx + 3 < n) {
    const float4 v = *(const float4*)&in[idx];
    ushort4 p;
    p.x = f2bf(v.x); p.y = f2bf(v.y); p.z = f2bf(v.z); p.w = f2bf(v.w);
    *(ushort4*)&out[idx] = p;
  }
}

__global__ __launch_bounds__(256) void zinit(ushort_t* __restrict__ z) {
  z[blockIdx.x * 256 + threadIdx.x] = 0;
}

// ---------------- launch ----------------
extern "C" void kernel_launch(void* const* d_in, const int* in_sizes, int n_in,
                              void* d_out, int out_size, void* d_ws, size_t ws_size,
                              hipStream_t stream) {
  const float* x_in     = (const float*)d_in[0];
  const float* patch_w  = (const float*)d_in[1];
  const float* patch_b  = (const float*)d_in[2];
  const float* pos_emb  = (const float*)d_in[3];
  const float* ln1_w    = (const float*)d_in[4];
  const float* ln1_b    = (const float*)d_in[5];
  const float* qkv_w    = (const float*)d_in[6];
  const float* qkv_b    = (const float*)d_in[7];
  const float* proj_w   = (const float*)d_in[8];
  const float* proj_b   = (const float*)d_in[9];
  const float* rel_h_w  = (const float*)d_in[10];
  const float* rel_w_w  = (const float*)d_in[11];
  const float* rel_h_g  = (const float*)d_in[12];
  const float* rel_w_g  = (const float*)d_in[13];
  const float* ln2_w    = (const float*)d_in[14];
  const float* ln2_b    = (const float*)d_in[15];
  const float* fc1_w    = (const float*)d_in[16];
  const float* fc1_b    = (const float*)d_in[17];
  const float* fc2_w    = (const float*)d_in[18];
  const float* fc2_b    = (const float*)d_in[19];
  const float* out_w    = (const float*)d_in[20];
  const float* out_b    = (const float*)d_in[21];
  float* outp = (float*)d_out;

  float* xbuf = (float*)d_ws;                                   // 2048*768 f32
  ushort_t* hb16    = (ushort_t*)(xbuf + (size_t)ROWS * E);     // 2048*768
  ushort_t* qkv16   = hb16 + (size_t)ROWS * E;                  // 3528*2304
  ushort_t* attnw16 = qkv16 + (size_t)WROWS * 3 * E;            // 3528*768
  ushort_t* wtbuf   = attnw16 + (size_t)WROWS * E;              // 9216*768
  ushort_t* wq = wtbuf;                 // 2304*768
  ushort_t* wp = wq + 2304 * 768;       // 768*768
  ushort_t* w1 = wp + 768 * 768;        // 3072*768
  ushort_t* w2 = w1 + 3072 * 768;       // 768*3072
  ushort_t* zbuf = wtbuf + (size_t)9216 * 768;  // 1024 zeros
  ushort_t* imb16 = hb16;
  ushort_t* h1b16 = qkv16;
  ushort_t* pwT16 = wtbuf;
  ushort_t* headW16 = wtbuf;

  zinit<<<4, 256, 0, stream>>>(zbuf);

  // ---- patch embed as GEMM ----
  cast_bf16<<<576, 256, 0, stream>>>(patch_w, pwT16, 768 * 768);
  im2col<<<ROWS, 256, 0, stream>>>(x_in, imb16);
  gemm_bt<OP_POS, 0><<<12 * 32, 256, 0, stream>>>(
      imb16, pwT16, patch_b, nullptr, pos_emb, nullptr, xbuf, ROWS, E, E, 12);

  int win_i = 0, glob_i = 0;
  for (int i = 0; i < 12; i++) {
    const bool is_win = (WIN_MASK >> i) & 1;

    prep_wt<<<6912, 256, 0, stream>>>(
        qkv_w + (size_t)i * E * 3 * E, proj_w + (size_t)i * E * E,
        fc1_w + (size_t)i * E * 4 * E, fc2_w + (size_t)i * 4 * E * E,
        wq, wp, w1, w2);

    ln_kernel<<<ROWS / 4, 256, 0, stream>>>(xbuf, ln1_w + i * E, ln1_b + i * E, hb16);

    if (is_win) {
      gemm_bt<OP_QKV, 1><<<36 * 56, 256, 0, stream>>>(
          hb16, wq, qkv_b + i * 3 * E, nullptr, nullptr, zbuf, qkv16,
          WROWS, 3 * E, E, 36);
      attn_mfma<<<dim3(7, BW * NH), 128, 0, stream>>>(
          qkv16, attnw16, rel_h_w + (size_t)win_i * (2 * WS - 1) * HD,
          rel_w_w + (size_t)win_i * (2 * WS - 1) * HD, WS, WS);
      win_i++;
    } else {
      gemm_bt<OP_QKV, 0><<<36 * 32, 256, 0, stream>>>(
          hb16, wq, qkv_b + i * 3 * E, nullptr, nullptr, nullptr, qkv16,
          ROWS, 3 * E, E, 36);
      attn_mfma<<<dim3(32, Bsz * NH), 128, 0, stream>>>(
          qkv16, attnw16, rel_h_g + (size_t)glob_i * (2 * G - 1) * HD,
          rel_w_g + (size_t)glob_i * (2 * G - 1) * HD, G, G);
      glob_i++;
    }

    if (is_win)
      gemm_bt<OP_ADD, 2><<<12 * 32, 256, 0, stream>>>(
          attnw16, wp, proj_b + i * E, xbuf, nullptr, nullptr, xbuf,
          ROWS, E, E, 12);
    else
      gemm_bt<OP_ADD, 0><<<12 * 32, 256, 0, stream>>>(
          attnw16, wp, proj_b + i * E, xbuf, nullptr, nullptr, xbuf,
          ROWS, E, E, 12);

    ln_kernel<<<ROWS / 4, 256, 0, stream>>>(xbuf, ln2_w + i * E, ln2_b + i * E, hb16);
    gemm_bt<OP_GELU, 0><<<48 * 32, 256, 0, stream>>>(
        hb16, w1, fc1_b + i * 4 * E, nullptr, nullptr, nullptr, h1b16,
        ROWS, 4 * E, E, 48);
    gemm_bt<OP_ADD, 0><<<12 * 32, 256, 0, stream>>>(
        h1b16, w2, fc2_b + i * E, xbuf, nullptr, nullptr, xbuf,
        ROWS, E, 4 * E, 12);
  }

  // ---- head ----
  cast_bf16<<<192, 256, 0, stream>>>(out_w, headW16, 256 * 768);
  cast_bf16<<<1536, 256, 0, stream>>>(xbuf, hb16, ROWS * E);
  gemm_bt<OP_HEAD, 0><<<4 * 32, 256, 0, stream>>>(
      hb16, headW16, out_b, nullptr, nullptr, nullptr, outp, ROWS, 256, E, 4);
}